// Round 6
// baseline (281.551 us; speedup 1.0000x reference)
//
#include <hip/hip_runtime.h>
#include <hip/hip_bf16.h>

// ---------------------------------------------------------------------------
// TransformerEncoder forward on MI355X (gfx950). Round 5:
//   - Round 4's tr_b16 GEMM with the ADDRESS FIX: per-lane tr-read address is
//     group_window + 8*c (natural contiguous pattern), not +2*c. The HW then
//     delivers column c of each 128B 4x16 row-major tile (m156 contract).
//   - Deeper split-K (8 slices) for emb/AO/FFN2; reduce kernels templated.
// ---------------------------------------------------------------------------

typedef __bf16 bf16_t;
typedef __bf16 bf16x4 __attribute__((ext_vector_type(4)));
typedef __bf16 bf16x8 __attribute__((ext_vector_type(8)));
typedef float  f32x4  __attribute__((ext_vector_type(4)));

#define SEQL 512
#define DM   2048
#define FFH  8192
#define NH   16
#define DHD  128
#define PST  ((size_t)SEQL*DM)   // partial-slice stride

__device__ __forceinline__ unsigned short bfbits(float f){
  bf16_t h = (bf16_t)f;
  return __builtin_bit_cast(unsigned short, h);
}
__device__ __forceinline__ unsigned int pack2(float a, float b){
  return (unsigned int)bfbits(a) | ((unsigned int)bfbits(b) << 16);
}

__device__ __forceinline__ void gll16(const bf16_t* g, bf16_t* l){
  __builtin_amdgcn_global_load_lds(
      (const __attribute__((address_space(1))) void*)g,
      (__attribute__((address_space(3))) void*)l, 16, 0, 0);
}
__device__ __forceinline__ unsigned lds_off(const void* p){
  return (unsigned)(uintptr_t)(const __attribute__((address_space(3))) void*)p;
}

// ---------------------------------------------------------------------------
// fp32 -> bf16 elementwise convert (for `sequence`)
__global__ __launch_bounds__(256)
void cvt_bf16(const float* __restrict__ in, bf16_t* __restrict__ out){
  const int i = (blockIdx.x * 256 + threadIdx.x) * 4;
  const float4 v = *(const float4*)(in + i);
  ushort4 o;
  o.x = bfbits(v.x); o.y = bfbits(v.y); o.z = bfbits(v.z); o.w = bfbits(v.w);
  *(ushort4*)(out + i) = o;
}

// ---------------------------------------------------------------------------
// GEMM: C[512][N] = A[512][K](bf16) @ W[K][N](fp32, HW-transposed via tr_b16).
// 64x128 tile, BK=32, 256 threads, 4 waves (wave w -> 32x64 sub-tile).
// B LDS layout per 32k x 128n tile (8 KB): for nf = n/16 (0..7):
//   byte(k, nc, nf) = nf*1024 + (k>>2)*128 + (k&3)*32 + nc*2   (4x16 row-major
//   tiles of 128B). tr-read: lane (c,g) addr = nf*1024 + g*256 + c*8
//   (+offset:128) -> receives W[8g+j][16nf+c], j=0..3 (resp. +4).
constexpr int E_PART = 0;  // fp32 partial (no bias) -> outF + zt*PST
constexpr int E_QKV  = 1;  // [0,2k)->Qf flat, [2k,4k)->Kf flat, rest->Vt[h][d][key]
constexpr int E_FFN1 = 2;  // bias + gelu -> bf16 [512][FFH]

template<int EPI, int PERM>
__global__ __launch_bounds__(256, 4)
void gemmF(const bf16_t* __restrict__ A,
           const float* __restrict__ W0p, const float* __restrict__ W1p,
           const float* __restrict__ W2p,
           const float* __restrict__ b0p, const float* __restrict__ b1p,
           const float* __restrict__ b2p,
           float* __restrict__ outF, bf16_t* __restrict__ o0,
           bf16_t* __restrict__ o1, bf16_t* __restrict__ o2,
           int nn, int Nw, int K, int Kc)
{
  __shared__ bf16_t sA[2][64*32];
  __shared__ bf16_t sB[2][128*32];
  const int tid  = threadIdx.x;
  const int lane = tid & 63, w = tid >> 6;
  const int wr4 = w >> 1, wc = w & 1;
  const int c = lane & 15, g = lane >> 4;

  // grid decode (XCD swizzle, m-fastest)
  const int nwg = gridDim.x, cpx = nwg >> 3;
  const int sblk = (blockIdx.x & 7) * cpx + (blockIdx.x >> 3);
  const int mt = sblk & 7, q2 = sblk >> 3;
  const int nt = q2 % nn, zt = q2 / nn;
  const int m0 = mt * 64, k0 = zt * Kc;

  // weight select (QKV: three separate [2048][2048] sources)
  const float* Wp = W0p; int nb0 = nt * 128;
  if constexpr (EPI == E_QKV){
    if (nt >= 32){ Wp = W2p; nb0 = (nt - 32) * 128; }
    else if (nt >= 16){ Wp = W1p; nb0 = (nt - 16) * 128; }
  }

  // A staging (global_load_lds, pre-swizzled 16B slot within each 64B k-row)
  const int sr = tid >> 2, ss = tid & 3;
  const int scol = ((ss ^ ((sr >> 1) & 3)) << 3);
  const bf16_t* Asrc = A + (size_t)(m0 + sr) * K + k0 + scol;

  // B staging: 2 slots/thread: slot q -> (k = sk + 16q, n8 = sn8)
  const int sk = tid >> 4, sn8 = tid & 15;
  const float* Wsrc = Wp + nb0 + sn8 * 8;
  unsigned bOff[2];
#pragma unroll
  for (int q = 0; q < 2; ++q)
    bOff[q] = (unsigned)((sn8 >> 1)*1024 + ((sk >> 2) + q*4)*128 + (sk & 3)*32 + (sn8 & 1)*16);

  const unsigned sBbase[2] = { lds_off(&sB[0][0]), lds_off(&sB[1][0]) };
  const unsigned trLane = (unsigned)(g*256 + c*8);   // <<< FIX: c*8, not c*2

  // A fragment read offsets
  int raA[2];
#pragma unroll
  for (int m = 0; m < 2; ++m){
    const int r = wr4*32 + m*16 + c;
    raA[m] = r*32 + ((g ^ ((r >> 1) & 3)) << 3);
  }

  f32x4 wv[2][2];

#define LOADW(kt) {                                                         \
    _Pragma("unroll")                                                       \
    for (int q = 0; q < 2; ++q){                                            \
      const int kr = k0 + (kt)*32 + sk + q*16;                              \
      const int krow = PERM ? (((kr & 127) << 4) + (kr >> 7)) : kr;         \
      wv[q][0] = *(const f32x4*)(Wsrc + (size_t)krow * Nw);                 \
      wv[q][1] = *(const f32x4*)(Wsrc + (size_t)krow * Nw + 4);             \
    } }

#define STAGEA(bf, kt) gll16(Asrc + (size_t)(kt)*32, &sA[bf][tid*8]);

#define WRITEB(bf) {                                                        \
    _Pragma("unroll")                                                       \
    for (int q = 0; q < 2; ++q){                                            \
      uint4 v;                                                              \
      v.x = pack2(wv[q][0][0], wv[q][0][1]);                                \
      v.y = pack2(wv[q][0][2], wv[q][0][3]);                                \
      v.z = pack2(wv[q][1][0], wv[q][1][1]);                                \
      v.w = pack2(wv[q][1][2], wv[q][1][3]);                                \
      *(uint4*)((char*)&sB[bf][0] + bOff[q]) = v;                           \
    } }

  f32x4 acc[2][4] = {};
  const int nk = Kc >> 5;

  LOADW(0);
  STAGEA(0, 0);
  WRITEB(0);
  __syncthreads();

  int buf = 0;
  for (int kt = 0; kt < nk; ++kt){
    const int nb = buf ^ 1;
    if (kt + 1 < nk){ LOADW(kt + 1); STAGEA(nb, kt + 1); }
    // fragments: A via C++ b128, B via hardware-transpose reads
    bf16x8 af[2], bq4[4];
#pragma unroll
    for (int m = 0; m < 2; ++m) af[m] = *(const bf16x8*)&sA[buf][raA[m]];
    {
      const unsigned base = sBbase[buf] + (unsigned)(wc*4*1024) + trLane;
#pragma unroll
      for (int n = 0; n < 4; ++n){
        bf16x4 r0, r1;
        const unsigned a = base + (unsigned)(n*1024);
        asm volatile("ds_read_b64_tr_b16 %0, %1" : "=v"(r0) : "v"(a));
        asm volatile("ds_read_b64_tr_b16 %0, %1 offset:128" : "=v"(r1) : "v"(a));
        bq4[n] = __builtin_shufflevector(r0, r1, 0,1,2,3,4,5,6,7);
      }
    }
    asm volatile("s_waitcnt lgkmcnt(0)" ::: "memory");
    __builtin_amdgcn_sched_barrier(0);
#pragma unroll
    for (int m = 0; m < 2; ++m)
#pragma unroll
      for (int n = 0; n < 4; ++n)
        acc[m][n] = __builtin_amdgcn_mfma_f32_16x16x32_bf16(af[m], bq4[n], acc[m][n], 0,0,0);
    if (kt + 1 < nk){ WRITEB(nb); }
    __syncthreads();
    buf = nb;
  }
#undef LOADW
#undef STAGEA
#undef WRITEB

  // epilogue: row = m0 + wr4*32 + m*16 + 4g + rr, col = nt*128 + wc*64 + n*16 + c
#pragma unroll
  for (int n = 0; n < 4; ++n){
    const int col = nt*128 + wc*64 + n*16 + c;
#pragma unroll
    for (int m = 0; m < 2; ++m){
      const int row0 = m0 + wr4*32 + m*16 + 4*g;
      const f32x4 a4 = acc[m][n];
      if constexpr (EPI == E_PART){
        float* dst = outF + (size_t)zt * PST;
#pragma unroll
        for (int rr = 0; rr < 4; ++rr)
          dst[(size_t)(row0+rr)*DM + col] = a4[rr];
      } else if constexpr (EPI == E_QKV){
        if (col < DM){
          const float bv = b0p[col];
#pragma unroll
          for (int rr = 0; rr < 4; ++rr)
            o0[(size_t)(row0+rr)*DM + col] = (bf16_t)(a4[rr] + bv);
        } else if (col < 2*DM){
          const int cc = col - DM;
          const float bv = b1p[cc];
#pragma unroll
          for (int rr = 0; rr < 4; ++rr)
            o1[(size_t)(row0+rr)*DM + cc] = (bf16_t)(a4[rr] + bv);
        } else {
          const int cc = col - 2*DM;
          const float bv = b2p[cc];
          const int hh = cc & 15, dd = cc >> 4;
          unsigned short us[4];
#pragma unroll
          for (int rr = 0; rr < 4; ++rr) us[rr] = bfbits(a4[rr] + bv);
          *(ushort4*)&o2[(size_t)(hh*DHD + dd)*SEQL + row0] =
              make_ushort4(us[0], us[1], us[2], us[3]);
        }
      } else if constexpr (EPI == E_FFN1){
        const float bv = b0p[col];
#pragma unroll
        for (int rr = 0; rr < 4; ++rr){
          const float v = a4[rr] + bv;
          const float z = v * (v*v*0.044715f + 1.0f) * 1.5957691216f;
          const float gg = v / (1.0f + __expf(-z));
          o0[(size_t)(row0+rr)*FFH + col] = (bf16_t)gg;
        }
      }
    }
  }
}

// ---------------------------------------------------------------------------
// Gather Q/K flat [row][16d+h] -> head layout [h][row][d] (pure bit-move).
__global__ __launch_bounds__(256)
void permute_qk(const bf16_t* __restrict__ Qf, const bf16_t* __restrict__ Kf,
                bf16_t* __restrict__ Qhd, bf16_t* __restrict__ Khd)
{
  const int row = blockIdx.x, which = blockIdx.y, tid = threadIdx.x;
  const bf16_t* src = (which ? Kf : Qf) + (size_t)row * DM;
  bf16_t* dst = which ? Khd : Qhd;
  const int hh = tid >> 4, d0 = (tid & 15) * 8;
  unsigned short us[8];
#pragma unroll
  for (int j = 0; j < 8; ++j)
    us[j] = __builtin_bit_cast(unsigned short, src[(d0 + j)*NH + hh]);
  uint4 o;
  o.x = (unsigned)us[0] | ((unsigned)us[1] << 16);
  o.y = (unsigned)us[2] | ((unsigned)us[3] << 16);
  o.z = (unsigned)us[4] | ((unsigned)us[5] << 16);
  o.w = (unsigned)us[6] | ((unsigned)us[7] << 16);
  *(uint4*)&dst[(size_t)hh*(SEQL*DHD) + (size_t)row*DHD + d0] = o;
}

// ---------------------------------------------------------------------------
// Attention: one block per (32 q-rows, head). Full softmax over 512 keys.
// Qh/Kh: [h][row][d]  Vt: [h][d][key]  Aout: [row][h*128+d] bf16
__global__ __launch_bounds__(256)
void attn_kernel(const bf16_t* __restrict__ Qh, const bf16_t* __restrict__ Kh,
                 const bf16_t* __restrict__ Vt, bf16_t* __restrict__ Aout)
{
  __shared__ bf16_t Pl[32*512];
  __shared__ float redm[4][32];
  __shared__ float reds[4][32];
  const int tid = threadIdx.x;
  const int lane = tid & 63, w = tid >> 6;
  const int c = lane & 15, g = lane >> 4;
  const int h = blockIdx.y;
  const int rb = blockIdx.x * 32;
  const bf16_t* Qb = Qh + (size_t)h * (SEQL*DHD);
  const bf16_t* Kb = Kh + (size_t)h * (SEQL*DHD);
  const bf16_t* Vb = Vt + (size_t)h * (SEQL*DHD);

  bf16x8 qf[2][4];
#pragma unroll
  for (int a = 0; a < 2; ++a)
#pragma unroll
    for (int ks = 0; ks < 4; ++ks)
      qf[a][ks] = *(const bf16x8*)(Qb + (size_t)(rb + a*16 + c)*DHD + ks*32 + g*8);

  f32x4 s[2][8] = {};
#pragma unroll
  for (int ks = 0; ks < 4; ++ks)
#pragma unroll
    for (int b = 0; b < 8; ++b){
      const bf16x8 kf = *(const bf16x8*)(Kb + (size_t)(w*128 + b*16 + c)*DHD + ks*32 + g*8);
      s[0][b] = __builtin_amdgcn_mfma_f32_16x16x32_bf16(qf[0][ks], kf, s[0][b], 0,0,0);
      s[1][b] = __builtin_amdgcn_mfma_f32_16x16x32_bf16(qf[1][ks], kf, s[1][b], 0,0,0);
    }
  // 1/sqrt(2048) score scale
#pragma unroll
  for (int a = 0; a < 2; ++a)
#pragma unroll
    for (int b = 0; b < 8; ++b)
#pragma unroll
      for (int rr = 0; rr < 4; ++rr) s[a][b][rr] *= 0.022097086912079612f;

  float mx[2][4], sm[2][4], inv[2][4];
#pragma unroll
  for (int a = 0; a < 2; ++a)
#pragma unroll
    for (int rr = 0; rr < 4; ++rr){
      float m = s[a][0][rr];
#pragma unroll
      for (int b = 1; b < 8; ++b) m = fmaxf(m, s[a][b][rr]);
#pragma unroll
      for (int off = 1; off < 16; off <<= 1) m = fmaxf(m, __shfl_xor(m, off));
      mx[a][rr] = m;
    }
  if (c == 0)
#pragma unroll
    for (int a = 0; a < 2; ++a)
#pragma unroll
      for (int rr = 0; rr < 4; ++rr) redm[w][a*16 + 4*g + rr] = mx[a][rr];
  __syncthreads();
#pragma unroll
  for (int a = 0; a < 2; ++a)
#pragma unroll
    for (int rr = 0; rr < 4; ++rr){
      const int lr = a*16 + 4*g + rr;
      mx[a][rr] = fmaxf(fmaxf(redm[0][lr], redm[1][lr]), fmaxf(redm[2][lr], redm[3][lr]));
      sm[a][rr] = 0.f;
    }
#pragma unroll
  for (int a = 0; a < 2; ++a)
#pragma unroll
    for (int b = 0; b < 8; ++b)
#pragma unroll
      for (int rr = 0; rr < 4; ++rr){
        const float p = __expf(s[a][b][rr] - mx[a][rr]);
        s[a][b][rr] = p;
        sm[a][rr] += p;
      }
#pragma unroll
  for (int a = 0; a < 2; ++a)
#pragma unroll
    for (int rr = 0; rr < 4; ++rr){
#pragma unroll
      for (int off = 1; off < 16; off <<= 1) sm[a][rr] += __shfl_xor(sm[a][rr], off);
    }
  if (c == 0)
#pragma unroll
    for (int a = 0; a < 2; ++a)
#pragma unroll
      for (int rr = 0; rr < 4; ++rr) reds[w][a*16 + 4*g + rr] = sm[a][rr];
  __syncthreads();
#pragma unroll
  for (int a = 0; a < 2; ++a)
#pragma unroll
    for (int rr = 0; rr < 4; ++rr){
      const int lr = a*16 + 4*g + rr;
      inv[a][rr] = 1.0f / (reds[0][lr] + reds[1][lr] + reds[2][lr] + reds[3][lr]);
    }

#pragma unroll
  for (int a = 0; a < 2; ++a)
#pragma unroll
    for (int b = 0; b < 8; ++b)
#pragma unroll
      for (int rr = 0; rr < 4; ++rr){
        const int lr  = a*16 + 4*g + rr;
        const int key = w*128 + b*16 + c;
        const int slot = (key >> 3) ^ (lr & 7);
        Pl[lr*512 + slot*8 + (key & 7)] = (bf16_t)(s[a][b][rr] * inv[a][rr]);
      }
  __syncthreads();

  f32x4 o[2][2] = {};
  const int dw = w * 32;
#pragma unroll
  for (int kst = 0; kst < 16; ++kst){
    bf16x8 pa2[2];
#pragma unroll
    for (int a = 0; a < 2; ++a){
      const int r = a*16 + c;
      const int slot = (kst*4 + g) ^ (r & 7);
      pa2[a] = *(const bf16x8*)&Pl[r*512 + slot*8];
    }
#pragma unroll
    for (int db = 0; db < 2; ++db){
      const bf16x8 vf = *(const bf16x8*)(Vb + (size_t)(dw + db*16 + c)*SEQL + kst*32 + g*8);
      o[0][db] = __builtin_amdgcn_mfma_f32_16x16x32_bf16(pa2[0], vf, o[0][db], 0,0,0);
      o[1][db] = __builtin_amdgcn_mfma_f32_16x16x32_bf16(pa2[1], vf, o[1][db], 0,0,0);
    }
  }
#pragma unroll
  for (int a = 0; a < 2; ++a)
#pragma unroll
    for (int db = 0; db < 2; ++db)
#pragma unroll
      for (int rr = 0; rr < 4; ++rr){
        const int row  = rb + a*16 + 4*g + rr;
        const int col2 = h*DHD + dw + db*16 + c;
        Aout[(size_t)row*DM + col2] = (bf16_t)o[a][db][rr];
      }
}

// ---------------------------------------------------------------------------
// reduce S split-K partials + bias + positional encoding -> X fp32 + XB bf16
template<int S>
__global__ __launch_bounds__(256)
void reduce_pos(const float* __restrict__ P, const float* __restrict__ bias,
                float* __restrict__ X, bf16_t* __restrict__ XB)
{
  const int row = blockIdx.x, c0 = threadIdx.x * 8;
  const size_t base = (size_t)row * DM + c0;
  float y[8];
#pragma unroll
  for (int j = 0; j < 8; ++j) y[j] = bias[c0 + j];
#pragma unroll
  for (int s = 0; s < S; ++s){
    const float4 v0 = *(const float4*)(P + s*PST + base);
    const float4 v1 = *(const float4*)(P + s*PST + base + 4);
    y[0]+=v0.x; y[1]+=v0.y; y[2]+=v0.z; y[3]+=v0.w;
    y[4]+=v1.x; y[5]+=v1.y; y[6]+=v1.z; y[7]+=v1.w;
  }
#pragma unroll
  for (int j = 0; j < 8; ++j){
    const int col = c0 + j;
    const float fr  = 1e-4f * __expf(-(float)(col >> 1) * (1.0f/1024.0f));
    const float ang = (float)row * fr;
    y[j] += (col & 1) ? __cosf(ang) : __sinf(ang);
  }
  *(float4*)(X + base)     = make_float4(y[0], y[1], y[2], y[3]);
  *(float4*)(X + base + 4) = make_float4(y[4], y[5], y[6], y[7]);
  uint4 ob;
  ob.x = pack2(y[0], y[1]); ob.y = pack2(y[2], y[3]);
  ob.z = pack2(y[4], y[5]); ob.w = pack2(y[6], y[7]);
  *(uint4*)&XB[base] = ob;
}

// ---------------------------------------------------------------------------
// reduce S split-K partials + bias + residual, then row-LayerNorm(2048).
template<int S, int WB>
__global__ __launch_bounds__(256)
void reduce_ln(const float* __restrict__ P, const float* __restrict__ bias,
               const float* __restrict__ resid, const float* __restrict__ gam,
               const float* __restrict__ bet, float* __restrict__ outF,
               bf16_t* __restrict__ outB)
{
  const int row = blockIdx.x, tid = threadIdx.x, c0 = tid * 8;
  const size_t base = (size_t)row * DM + c0;
  float y[8];
  {
    const float4 r0 = *(const float4*)(resid + base);
    const float4 r1 = *(const float4*)(resid + base + 4);
    y[0]=r0.x; y[1]=r0.y; y[2]=r0.z; y[3]=r0.w;
    y[4]=r1.x; y[5]=r1.y; y[6]=r1.z; y[7]=r1.w;
  }
#pragma unroll
  for (int j = 0; j < 8; ++j) y[j] += bias[c0 + j];
#pragma unroll
  for (int s = 0; s < S; ++s){
    const float4 v0 = *(const float4*)(P + s*PST + base);
    const float4 v1 = *(const float4*)(P + s*PST + base + 4);
    y[0]+=v0.x; y[1]+=v0.y; y[2]+=v0.z; y[3]+=v0.w;
    y[4]+=v1.x; y[5]+=v1.y; y[6]+=v1.z; y[7]+=v1.w;
  }
  float sm = 0.f, qs = 0.f;
#pragma unroll
  for (int j = 0; j < 8; ++j){ sm += y[j]; qs += y[j]*y[j]; }
#pragma unroll
  for (int off = 32; off >= 1; off >>= 1){
    sm += __shfl_xor(sm, off); qs += __shfl_xor(qs, off);
  }
  __shared__ float rs[4], rq[4];
  const int w = tid >> 6;
  if ((tid & 63) == 0){ rs[w] = sm; rq[w] = qs; }
  __syncthreads();
  sm = rs[0]+rs[1]+rs[2]+rs[3];
  qs = rq[0]+rq[1]+rq[2]+rq[3];
  const float mu   = sm * (1.0f/2048.0f);
  const float var  = qs * (1.0f/2048.0f) - mu*mu;
  const float rstd = rsqrtf(var + 1e-5f);
  const float4 g0 = *(const float4*)(gam + c0);
  const float4 g1 = *(const float4*)(gam + c0 + 4);
  const float4 b0 = *(const float4*)(bet + c0);
  const float4 b1 = *(const float4*)(bet + c0 + 4);
  float o[8];
  o[0] = (y[0]-mu)*rstd*g0.x + b0.x;  o[1] = (y[1]-mu)*rstd*g0.y + b0.y;
  o[2] = (y[2]-mu)*rstd*g0.z + b0.z;  o[3] = (y[3]-mu)*rstd*g0.w + b0.w;
  o[4] = (y[4]-mu)*rstd*g1.x + b1.x;  o[5] = (y[5]-mu)*rstd*g1.y + b1.y;
  o[6] = (y[6]-mu)*rstd*g1.z + b1.z;  o[7] = (y[7]-mu)*rstd*g1.w + b1.w;
  *(float4*)(outF + base)     = make_float4(o[0], o[1], o[2], o[3]);
  *(float4*)(outF + base + 4) = make_float4(o[4], o[5], o[6], o[7]);
  if constexpr (WB){
    uint4 ob;
    ob.x = pack2(o[0], o[1]); ob.y = pack2(o[2], o[3]);
    ob.z = pack2(o[4], o[5]); ob.w = pack2(o[6], o[7]);
    *(uint4*)&outB[base] = ob;
  }
}

// ---------------------------------------------------------------------------
extern "C" void kernel_launch(void* const* d_in, const int* in_sizes, int n_in,
                              void* d_out, int out_size, void* d_ws, size_t ws_size,
                              hipStream_t stream)
{
  const float* seq   = (const float*)d_in[0];
  const float* emb_W = (const float*)d_in[1];
  const float* emb_b = (const float*)d_in[2];
  const float* Wq = (const float*)d_in[3];  const float* bq = (const float*)d_in[4];
  const float* Wk = (const float*)d_in[5];  const float* bk = (const float*)d_in[6];
  const float* Wv = (const float*)d_in[7];  const float* bv = (const float*)d_in[8];
  const float* Wo = (const float*)d_in[9];  const float* bo = (const float*)d_in[10];
  const float* ln_g = (const float*)d_in[11]; const float* ln_b = (const float*)d_in[12];
  const float* W1 = (const float*)d_in[13]; const float* b1 = (const float*)d_in[14];
  const float* W2 = (const float*)d_in[15]; const float* b2 = (const float*)d_in[16];

  char* ws = (char*)d_ws;
  size_t off = 0;
  auto take = [&](size_t bytes) -> void* {
    void* p = ws + off;
    off += (bytes + 255) & ~(size_t)255;
    return p;
  };
  bf16_t* seqB = (bf16_t*)take((size_t)SEQL*DM*2);
  float*  X    = (float*) take((size_t)SEQL*DM*4);
  bf16_t* XB   = (bf16_t*)take((size_t)SEQL*DM*2);
  bf16_t* Qf   = (bf16_t*)take((size_t)SEQL*DM*2);
  bf16_t* Kf   = (bf16_t*)take((size_t)SEQL*DM*2);
  bf16_t* Qhd  = (bf16_t*)take((size_t)SEQL*DM*2);
  bf16_t* Khd  = (bf16_t*)take((size_t)SEQL*DM*2);
  bf16_t* Vt   = (bf16_t*)take((size_t)SEQL*DM*2);
  bf16_t* Afl  = (bf16_t*)take((size_t)SEQL*DM*2);
  float*  Pp   = (float*) take((size_t)8*SEQL*DM*4);  // split-K partials (32 MB)
  float*  Xa   = (float*) take((size_t)SEQL*DM*4);
  bf16_t* XaB  = (bf16_t*)take((size_t)SEQL*DM*2);
  bf16_t* Hb   = (bf16_t*)take((size_t)SEQL*FFH*2);
  (void)ws_size; (void)in_sizes; (void)n_in; (void)out_size;

  // sequence fp32 -> bf16
  cvt_bf16<<<dim3(SEQL*DM/1024), 256, 0, stream>>>(seq, seqB);

  // embedding (split-K x8, 1024 blocks) + posenc reduce
  gemmF<E_PART,0><<<dim3(1024), 256, 0, stream>>>(seqB, emb_W, nullptr, nullptr,
      nullptr, nullptr, nullptr, Pp, nullptr, nullptr, nullptr, 16, DM, DM, 256);
  reduce_pos<8><<<SEQL, 256, 0, stream>>>(Pp, emb_b, X, XB);

  // fused QKV (384 blocks)
  gemmF<E_QKV,0><<<dim3(384), 256, 0, stream>>>(XB, Wq, Wk, Wv,
      bq, bk, bv, nullptr, Qf, Kf, Vt, 48, DM, DM, DM);
  permute_qk<<<dim3(SEQL,2), 256, 0, stream>>>(Qf, Kf, Qhd, Khd);

  // attention
  attn_kernel<<<dim3(16,16), 256, 0, stream>>>(Qhd, Khd, Vt, Afl);

  // output projection (split-K x8, k-permuted Wo) + residual + LN1
  gemmF<E_PART,1><<<dim3(1024), 256, 0, stream>>>(Afl, Wo, nullptr, nullptr,
      nullptr, nullptr, nullptr, Pp, nullptr, nullptr, nullptr, 16, DM, DM, 256);
  reduce_ln<8,1><<<SEQL, 256, 0, stream>>>(Pp, bo, X, ln_g, ln_b, Xa, XaB);

  // FFN1 (512 blocks)
  gemmF<E_FFN1,0><<<dim3(512), 256, 0, stream>>>(XaB, W1, nullptr, nullptr,
      b1, nullptr, nullptr, nullptr, Hb, nullptr, nullptr, 64, FFH, DM, DM);

  // FFN2 (split-K x8, Kc=1024) + residual + LN2 -> out
  gemmF<E_PART,0><<<dim3(1024), 256, 0, stream>>>(Hb, W2, nullptr, nullptr,
      nullptr, nullptr, nullptr, Pp, nullptr, nullptr, nullptr, 16, DM, FFH, 1024);
  reduce_ln<8,0><<<SEQL, 256, 0, stream>>>(Pp, b2, Xa, ln_g, ln_b, (float*)d_out, nullptr);
}

// Round 7
// 277.109 us; speedup vs baseline: 1.0160x; 1.0160x over previous
//
#include <hip/hip_runtime.h>
#include <hip/hip_bf16.h>

// ---------------------------------------------------------------------------
// TransformerEncoder forward on MI355X (gfx950). Round 6:
//   - GEMM pipeline: 2-deep W register prefetch across RAW s_barrier with
//     counted vmcnt(4) (A-gll issued first, W loads stay in flight across the
//     barrier). Two named register stages, loop unrolled x2 (static indices).
//   - BM=32 template variant for QKV (grid 768) and FFN1 (grid 1024).
//   - B-operand via hardware ds_read_b64_tr_b16 (round 5, verified).
// ---------------------------------------------------------------------------

typedef __bf16 bf16_t;
typedef __bf16 bf16x4 __attribute__((ext_vector_type(4)));
typedef __bf16 bf16x8 __attribute__((ext_vector_type(8)));
typedef float  f32x4  __attribute__((ext_vector_type(4)));

#define SEQL 512
#define DM   2048
#define FFH  8192
#define NH   16
#define DHD  128
#define PST  ((size_t)SEQL*DM)   // partial-slice stride

__device__ __forceinline__ unsigned short bfbits(float f){
  bf16_t h = (bf16_t)f;
  return __builtin_bit_cast(unsigned short, h);
}
__device__ __forceinline__ unsigned int pack2(float a, float b){
  return (unsigned int)bfbits(a) | ((unsigned int)bfbits(b) << 16);
}

__device__ __forceinline__ void gll16(const bf16_t* g, bf16_t* l){
  __builtin_amdgcn_global_load_lds(
      (const __attribute__((address_space(1))) void*)g,
      (__attribute__((address_space(3))) void*)l, 16, 0, 0);
}
__device__ __forceinline__ unsigned lds_off(const void* p){
  return (unsigned)(uintptr_t)(const __attribute__((address_space(3))) void*)p;
}

// ---------------------------------------------------------------------------
// fp32 -> bf16 elementwise convert (for `sequence`)
__global__ __launch_bounds__(256)
void cvt_bf16(const float* __restrict__ in, bf16_t* __restrict__ out){
  const int i = (blockIdx.x * 256 + threadIdx.x) * 4;
  const float4 v = *(const float4*)(in + i);
  ushort4 o;
  o.x = bfbits(v.x); o.y = bfbits(v.y); o.z = bfbits(v.z); o.w = bfbits(v.w);
  *(ushort4*)(out + i) = o;
}

// ---------------------------------------------------------------------------
// GEMM: C[512][N] = A[512][K](bf16) @ W[K][N](fp32, HW-transposed via tr_b16).
// BMx128 tile (BM=64 or 32), BK=32, 256 threads, 4 waves.
//   BM=64: wave -> 32m x 64n (2x4 frags).  BM=32: wave -> 32m x 32n (2x2).
// B LDS per 32k x 128n tile: nf-th 16-col group at nf*1024, 4x16 row-major
// 128B subtiles; tr-read lane(c,g) addr = nf*1024 + g*256 + c*8 (+offset:128)
// -> W[8g+j][16nf+c].
constexpr int E_PART = 0;  // fp32 partial (no bias) -> outF + zt*PST
constexpr int E_QKV  = 1;  // [0,2k)->Qf flat, [2k,4k)->Kf flat, rest->Vt[h][d][key]
constexpr int E_FFN1 = 2;  // bias + gelu -> bf16 [512][FFH]

template<int EPI, int PERM, int BM>
__global__ __launch_bounds__(256, 4)
void gemmF(const bf16_t* __restrict__ A,
           const float* __restrict__ W0p, const float* __restrict__ W1p,
           const float* __restrict__ W2p,
           const float* __restrict__ b0p, const float* __restrict__ b1p,
           const float* __restrict__ b2p,
           float* __restrict__ outF, bf16_t* __restrict__ o0,
           bf16_t* __restrict__ o1, bf16_t* __restrict__ o2,
           int nn, int Nw, int K, int Kc)
{
  constexpr int NF  = (BM == 64) ? 4 : 2;   // n-frags per wave
  constexpr int MTM = (BM == 64) ? 7 : 15;  // m-tile mask
  constexpr int MTS = (BM == 64) ? 3 : 4;   // m-tile shift
  __shared__ bf16_t sA[2][BM*32];
  __shared__ bf16_t sB[2][128*32];
  const int tid  = threadIdx.x;
  const int lane = tid & 63, w = tid >> 6;
  const int wr4 = (BM == 64) ? (w >> 1) : 0;
  const int wc  = (BM == 64) ? (w & 1)  : w;
  const int c = lane & 15, g = lane >> 4;

  // grid decode (XCD swizzle, m-fastest)
  const int nwg = gridDim.x, cpx = nwg >> 3;
  const int sblk = (blockIdx.x & 7) * cpx + (blockIdx.x >> 3);
  const int mt = sblk & MTM, q2 = sblk >> MTS;
  const int nt = q2 % nn, zt = q2 / nn;
  const int m0 = mt * BM, k0 = zt * Kc;

  // weight select (QKV: three separate [2048][2048] sources)
  const float* Wp = W0p; int nb0 = nt * 128;
  if constexpr (EPI == E_QKV){
    if (nt >= 32){ Wp = W2p; nb0 = (nt - 32) * 128; }
    else if (nt >= 16){ Wp = W1p; nb0 = (nt - 16) * 128; }
  }

  // A staging (global_load_lds, pre-swizzled 16B slot within each 64B k-row)
  const bool doA = (BM == 64) || (tid < 128);
  const int sr = tid >> 2, ss = tid & 3;
  const int scol = ((ss ^ ((sr >> 1) & 3)) << 3);
  const bf16_t* Asrc = A + (size_t)(m0 + sr) * K + k0 + scol;

  // B staging: 2 slots/thread: slot q -> (k = sk + 16q, 8 cols at 8*sn8)
  const int sk = tid >> 4, sn8 = tid & 15;
  const float* Wsrc = Wp + nb0 + sn8 * 8;
  unsigned bOff[2];
#pragma unroll
  for (int q = 0; q < 2; ++q)
    bOff[q] = (unsigned)((sn8 >> 1)*1024 + ((sk >> 2) + q*4)*128 + (sk & 3)*32 + (sn8 & 1)*16);

  const unsigned sBbase[2] = { lds_off(&sB[0][0]), lds_off(&sB[1][0]) };
  const unsigned trLane = (unsigned)(g*256 + c*8);

  // A fragment read offsets
  int raA[2];
#pragma unroll
  for (int m = 0; m < 2; ++m){
    const int r = wr4*32 + m*16 + c;
    raA[m] = r*32 + ((g ^ ((r >> 1) & 3)) << 3);
  }

  f32x4 wv0[2][2], wv1[2][2];   // two named W prefetch stages (static indices)
  f32x4 acc[2][NF] = {};
  const int nk = Kc >> 5;

#define LOADW(SV, kt) {                                                     \
    _Pragma("unroll")                                                       \
    for (int q = 0; q < 2; ++q){                                            \
      const int kr = k0 + (kt)*32 + sk + q*16;                              \
      const int krow = PERM ? (((kr & 127) << 4) + (kr >> 7)) : kr;         \
      SV[q][0] = *(const f32x4*)(Wsrc + (size_t)krow * Nw);                 \
      SV[q][1] = *(const f32x4*)(Wsrc + (size_t)krow * Nw + 4);             \
    } }

#define STAGEA(bf, kt) { if (doA) gll16(Asrc + (size_t)(kt)*32, &sA[bf][tid*8]); }

#define WRITEB(bf, SV) {                                                    \
    _Pragma("unroll")                                                       \
    for (int q = 0; q < 2; ++q){                                            \
      uint4 v;                                                              \
      v.x = pack2(SV[q][0][0], SV[q][0][1]);                                \
      v.y = pack2(SV[q][0][2], SV[q][0][3]);                                \
      v.z = pack2(SV[q][1][0], SV[q][1][1]);                                \
      v.w = pack2(SV[q][1][2], SV[q][1][3]);                                \
      *(uint4*)((char*)&sB[bf][0] + bOff[q]) = v;                           \
    } }

#define COMPUTE(PB) {                                                       \
    bf16x8 af[2]; bf16x8 bq4[NF];                                           \
    _Pragma("unroll")                                                       \
    for (int m = 0; m < 2; ++m) af[m] = *(const bf16x8*)&sA[PB][raA[m]];    \
    { const unsigned base = sBbase[PB] + (unsigned)(wc*NF*1024) + trLane;   \
      _Pragma("unroll")                                                     \
      for (int n = 0; n < NF; ++n){                                         \
        bf16x4 r0, r1; const unsigned a2 = base + (unsigned)(n*1024);       \
        asm volatile("ds_read_b64_tr_b16 %0, %1" : "=v"(r0) : "v"(a2));     \
        asm volatile("ds_read_b64_tr_b16 %0, %1 offset:128" : "=v"(r1) : "v"(a2)); \
        bq4[n] = __builtin_shufflevector(r0, r1, 0,1,2,3,4,5,6,7);          \
      } }                                                                   \
    asm volatile("s_waitcnt lgkmcnt(0)" ::: "memory");                      \
    __builtin_amdgcn_sched_barrier(0);                                      \
    _Pragma("unroll")                                                       \
    for (int m = 0; m < 2; ++m)                                             \
      _Pragma("unroll")                                                     \
      for (int n = 0; n < NF; ++n)                                          \
        acc[m][n] = __builtin_amdgcn_mfma_f32_16x16x32_bf16(af[m], bq4[n], acc[m][n], 0,0,0); }

// iter kt: stage A(kt+1); issue W(kt+2) into SLOAD; compute buf PB;
// write B(kt+1) from SCONS; vmcnt(4) keeps W(kt+2) in flight across barrier.
#define ITER(kt, PB, SLOAD, SCONS) {                                        \
    const bool h1 = (kt) + 1 < nk, h2 = (kt) + 2 < nk;                      \
    if (h1) STAGEA(PB^1, (kt)+1);                                           \
    __builtin_amdgcn_sched_barrier(0);                                      \
    if (h2) LOADW(SLOAD, (kt)+2);                                           \
    __builtin_amdgcn_sched_barrier(0);                                      \
    COMPUTE(PB);                                                            \
    if (h1){                                                                \
      WRITEB(PB^1, SCONS);                                                  \
      if (h2) asm volatile("s_waitcnt vmcnt(4) lgkmcnt(0)" ::: "memory");   \
      else    asm volatile("s_waitcnt vmcnt(0) lgkmcnt(0)" ::: "memory");   \
      __builtin_amdgcn_s_barrier();                                         \
      __builtin_amdgcn_sched_barrier(0);                                    \
    } }

  // prologue: A(0) first (oldest in vm FIFO), then W(0), W(1)
  STAGEA(0, 0);
  __builtin_amdgcn_sched_barrier(0);
  LOADW(wv0, 0);
  LOADW(wv1, 1);
  __builtin_amdgcn_sched_barrier(0);
  WRITEB(0, wv0);                                    // compiler waits W(0)
  asm volatile("s_waitcnt vmcnt(4) lgkmcnt(0)" ::: "memory");  // retires A(0)
  __builtin_amdgcn_s_barrier();
  __builtin_amdgcn_sched_barrier(0);

  for (int kt = 0; kt < nk; kt += 2){
    ITER(kt,     0, wv0, wv1);
    ITER(kt + 1, 1, wv1, wv0);
  }
#undef LOADW
#undef STAGEA
#undef WRITEB
#undef COMPUTE
#undef ITER

  // epilogue: row = m0 + wr4*32 + m*16 + 4g + rr, col = nt*128 + wc*(NF*16) + n*16 + c
#pragma unroll
  for (int n = 0; n < NF; ++n){
    const int col = nt*128 + wc*(NF*16) + n*16 + c;
#pragma unroll
    for (int m = 0; m < 2; ++m){
      const int row0 = m0 + wr4*32 + m*16 + 4*g;
      const f32x4 a4 = acc[m][n];
      if constexpr (EPI == E_PART){
        float* dst = outF + (size_t)zt * PST;
#pragma unroll
        for (int rr = 0; rr < 4; ++rr)
          dst[(size_t)(row0+rr)*DM + col] = a4[rr];
      } else if constexpr (EPI == E_QKV){
        if (col < DM){
          const float bv = b0p[col];
#pragma unroll
          for (int rr = 0; rr < 4; ++rr)
            o0[(size_t)(row0+rr)*DM + col] = (bf16_t)(a4[rr] + bv);
        } else if (col < 2*DM){
          const int cc = col - DM;
          const float bv = b1p[cc];
#pragma unroll
          for (int rr = 0; rr < 4; ++rr)
            o1[(size_t)(row0+rr)*DM + cc] = (bf16_t)(a4[rr] + bv);
        } else {
          const int cc = col - 2*DM;
          const float bv = b2p[cc];
          const int hh = cc & 15, dd = cc >> 4;
          unsigned short us[4];
#pragma unroll
          for (int rr = 0; rr < 4; ++rr) us[rr] = bfbits(a4[rr] + bv);
          *(ushort4*)&o2[(size_t)(hh*DHD + dd)*SEQL + row0] =
              make_ushort4(us[0], us[1], us[2], us[3]);
        }
      } else if constexpr (EPI == E_FFN1){
        const float bv = b0p[col];
#pragma unroll
        for (int rr = 0; rr < 4; ++rr){
          const float v = a4[rr] + bv;
          const float z = v * (v*v*0.044715f + 1.0f) * 1.5957691216f;
          const float gg = v / (1.0f + __expf(-z));
          o0[(size_t)(row0+rr)*FFH + col] = (bf16_t)gg;
        }
      }
    }
  }
}

// ---------------------------------------------------------------------------
// Gather Q/K flat [row][16d+h] -> head layout [h][row][d] (pure bit-move).
__global__ __launch_bounds__(256)
void permute_qk(const bf16_t* __restrict__ Qf, const bf16_t* __restrict__ Kf,
                bf16_t* __restrict__ Qhd, bf16_t* __restrict__ Khd)
{
  const int row = blockIdx.x, which = blockIdx.y, tid = threadIdx.x;
  const bf16_t* src = (which ? Kf : Qf) + (size_t)row * DM;
  bf16_t* dst = which ? Khd : Qhd;
  const int hh = tid >> 4, d0 = (tid & 15) * 8;
  unsigned short us[8];
#pragma unroll
  for (int j = 0; j < 8; ++j)
    us[j] = __builtin_bit_cast(unsigned short, src[(d0 + j)*NH + hh]);
  uint4 o;
  o.x = (unsigned)us[0] | ((unsigned)us[1] << 16);
  o.y = (unsigned)us[2] | ((unsigned)us[3] << 16);
  o.z = (unsigned)us[4] | ((unsigned)us[5] << 16);
  o.w = (unsigned)us[6] | ((unsigned)us[7] << 16);
  *(uint4*)&dst[(size_t)hh*(SEQL*DHD) + (size_t)row*DHD + d0] = o;
}

// ---------------------------------------------------------------------------
// Attention: one block per (32 q-rows, head). Full softmax over 512 keys.
// Qh/Kh: [h][row][d]  Vt: [h][d][key]  Aout: [row][h*128+d] bf16
__global__ __launch_bounds__(256)
void attn_kernel(const bf16_t* __restrict__ Qh, const bf16_t* __restrict__ Kh,
                 const bf16_t* __restrict__ Vt, bf16_t* __restrict__ Aout)
{
  __shared__ bf16_t Pl[32*512];
  __shared__ float redm[4][32];
  __shared__ float reds[4][32];
  const int tid = threadIdx.x;
  const int lane = tid & 63, w = tid >> 6;
  const int c = lane & 15, g = lane >> 4;
  const int h = blockIdx.y;
  const int rb = blockIdx.x * 32;
  const bf16_t* Qb = Qh + (size_t)h * (SEQL*DHD);
  const bf16_t* Kb = Kh + (size_t)h * (SEQL*DHD);
  const bf16_t* Vb = Vt + (size_t)h * (SEQL*DHD);

  bf16x8 qf[2][4];
#pragma unroll
  for (int a = 0; a < 2; ++a)
#pragma unroll
    for (int ks = 0; ks < 4; ++ks)
      qf[a][ks] = *(const bf16x8*)(Qb + (size_t)(rb + a*16 + c)*DHD + ks*32 + g*8);

  f32x4 s[2][8] = {};
#pragma unroll
  for (int ks = 0; ks < 4; ++ks)
#pragma unroll
    for (int b = 0; b < 8; ++b){
      const bf16x8 kf = *(const bf16x8*)(Kb + (size_t)(w*128 + b*16 + c)*DHD + ks*32 + g*8);
      s[0][b] = __builtin_amdgcn_mfma_f32_16x16x32_bf16(qf[0][ks], kf, s[0][b], 0,0,0);
      s[1][b] = __builtin_amdgcn_mfma_f32_16x16x32_bf16(qf[1][ks], kf, s[1][b], 0,0,0);
    }
  // 1/sqrt(2048) score scale
#pragma unroll
  for (int a = 0; a < 2; ++a)
#pragma unroll
    for (int b = 0; b < 8; ++b)
#pragma unroll
      for (int rr = 0; rr < 4; ++rr) s[a][b][rr] *= 0.022097086912079612f;

  float mx[2][4], sm[2][4], inv[2][4];
#pragma unroll
  for (int a = 0; a < 2; ++a)
#pragma unroll
    for (int rr = 0; rr < 4; ++rr){
      float m = s[a][0][rr];
#pragma unroll
      for (int b = 1; b < 8; ++b) m = fmaxf(m, s[a][b][rr]);
#pragma unroll
      for (int off = 1; off < 16; off <<= 1) m = fmaxf(m, __shfl_xor(m, off));
      mx[a][rr] = m;
    }
  if (c == 0)
#pragma unroll
    for (int a = 0; a < 2; ++a)
#pragma unroll
      for (int rr = 0; rr < 4; ++rr) redm[w][a*16 + 4*g + rr] = mx[a][rr];
  __syncthreads();
#pragma unroll
  for (int a = 0; a < 2; ++a)
#pragma unroll
    for (int rr = 0; rr < 4; ++rr){
      const int lr = a*16 + 4*g + rr;
      mx[a][rr] = fmaxf(fmaxf(redm[0][lr], redm[1][lr]), fmaxf(redm[2][lr], redm[3][lr]));
      sm[a][rr] = 0.f;
    }
#pragma unroll
  for (int a = 0; a < 2; ++a)
#pragma unroll
    for (int b = 0; b < 8; ++b)
#pragma unroll
      for (int rr = 0; rr < 4; ++rr){
        const float p = __expf(s[a][b][rr] - mx[a][rr]);
        s[a][b][rr] = p;
        sm[a][rr] += p;
      }
#pragma unroll
  for (int a = 0; a < 2; ++a)
#pragma unroll
    for (int rr = 0; rr < 4; ++rr){
#pragma unroll
      for (int off = 1; off < 16; off <<= 1) sm[a][rr] += __shfl_xor(sm[a][rr], off);
    }
  if (c == 0)
#pragma unroll
    for (int a = 0; a < 2; ++a)
#pragma unroll
      for (int rr = 0; rr < 4; ++rr) reds[w][a*16 + 4*g + rr] = sm[a][rr];
  __syncthreads();
#pragma unroll
  for (int a = 0; a < 2; ++a)
#pragma unroll
    for (int rr = 0; rr < 4; ++rr){
      const int lr = a*16 + 4*g + rr;
      inv[a][rr] = 1.0f / (reds[0][lr] + reds[1][lr] + reds[2][lr] + reds[3][lr]);
    }

#pragma unroll
  for (int a = 0; a < 2; ++a)
#pragma unroll
    for (int b = 0; b < 8; ++b)
#pragma unroll
      for (int rr = 0; rr < 4; ++rr){
        const int lr  = a*16 + 4*g + rr;
        const int key = w*128 + b*16 + c;
        const int slot = (key >> 3) ^ (lr & 7);
        Pl[lr*512 + slot*8 + (key & 7)] = (bf16_t)(s[a][b][rr] * inv[a][rr]);
      }
  __syncthreads();

  f32x4 o[2][2] = {};
  const int dw = w * 32;
#pragma unroll
  for (int kst = 0; kst < 16; ++kst){
    bf16x8 pa2[2];
#pragma unroll
    for (int a = 0; a < 2; ++a){
      const int r = a*16 + c;
      const int slot = (kst*4 + g) ^ (r & 7);
      pa2[a] = *(const bf16x8*)&Pl[r*512 + slot*8];
    }
#pragma unroll
    for (int db = 0; db < 2; ++db){
      const bf16x8 vf = *(const bf16x8*)(Vb + (size_t)(dw + db*16 + c)*SEQL + kst*32 + g*8);
      o[0][db] = __builtin_amdgcn_mfma_f32_16x16x32_bf16(pa2[0], vf, o[0][db], 0,0,0);
      o[1][db] = __builtin_amdgcn_mfma_f32_16x16x32_bf16(pa2[1], vf, o[1][db], 0,0,0);
    }
  }
#pragma unroll
  for (int a = 0; a < 2; ++a)
#pragma unroll
    for (int db = 0; db < 2; ++db)
#pragma unroll
      for (int rr = 0; rr < 4; ++rr){
        const int row  = rb + a*16 + 4*g + rr;
        const int col2 = h*DHD + dw + db*16 + c;
        Aout[(size_t)row*DM + col2] = (bf16_t)o[a][db][rr];
      }
}

// ---------------------------------------------------------------------------
// reduce S split-K partials + bias + positional encoding -> X fp32 + XB bf16
template<int S>
__global__ __launch_bounds__(256)
void reduce_pos(const float* __restrict__ P, const float* __restrict__ bias,
                float* __restrict__ X, bf16_t* __restrict__ XB)
{
  const int row = blockIdx.x, c0 = threadIdx.x * 8;
  const size_t base = (size_t)row * DM + c0;
  float y[8];
#pragma unroll
  for (int j = 0; j < 8; ++j) y[j] = bias[c0 + j];
#pragma unroll
  for (int s = 0; s < S; ++s){
    const float4 v0 = *(const float4*)(P + s*PST + base);
    const float4 v1 = *(const float4*)(P + s*PST + base + 4);
    y[0]+=v0.x; y[1]+=v0.y; y[2]+=v0.z; y[3]+=v0.w;
    y[4]+=v1.x; y[5]+=v1.y; y[6]+=v1.z; y[7]+=v1.w;
  }
#pragma unroll
  for (int j = 0; j < 8; ++j){
    const int col = c0 + j;
    const float fr  = 1e-4f * __expf(-(float)(col >> 1) * (1.0f/1024.0f));
    const float ang = (float)row * fr;
    y[j] += (col & 1) ? __cosf(ang) : __sinf(ang);
  }
  *(float4*)(X + base)     = make_float4(y[0], y[1], y[2], y[3]);
  *(float4*)(X + base + 4) = make_float4(y[4], y[5], y[6], y[7]);
  uint4 ob;
  ob.x = pack2(y[0], y[1]); ob.y = pack2(y[2], y[3]);
  ob.z = pack2(y[4], y[5]); ob.w = pack2(y[6], y[7]);
  *(uint4*)&XB[base] = ob;
}

// ---------------------------------------------------------------------------
// reduce S split-K partials + bias + residual, then row-LayerNorm(2048).
template<int S, int WB>
__global__ __launch_bounds__(256)
void reduce_ln(const float* __restrict__ P, const float* __restrict__ bias,
               const float* __restrict__ resid, const float* __restrict__ gam,
               const float* __restrict__ bet, float* __restrict__ outF,
               bf16_t* __restrict__ outB)
{
  const int row = blockIdx.x, tid = threadIdx.x, c0 = tid * 8;
  const size_t base = (size_t)row * DM + c0;
  float y[8];
  {
    const float4 r0 = *(const float4*)(resid + base);
    const float4 r1 = *(const float4*)(resid + base + 4);
    y[0]=r0.x; y[1]=r0.y; y[2]=r0.z; y[3]=r0.w;
    y[4]=r1.x; y[5]=r1.y; y[6]=r1.z; y[7]=r1.w;
  }
#pragma unroll
  for (int j = 0; j < 8; ++j) y[j] += bias[c0 + j];
#pragma unroll
  for (int s = 0; s < S; ++s){
    const float4 v0 = *(const float4*)(P + s*PST + base);
    const float4 v1 = *(const float4*)(P + s*PST + base + 4);
    y[0]+=v0.x; y[1]+=v0.y; y[2]+=v0.z; y[3]+=v0.w;
    y[4]+=v1.x; y[5]+=v1.y; y[6]+=v1.z; y[7]+=v1.w;
  }
  float sm = 0.f, qs = 0.f;
#pragma unroll
  for (int j = 0; j < 8; ++j){ sm += y[j]; qs += y[j]*y[j]; }
#pragma unroll
  for (int off = 32; off >= 1; off >>= 1){
    sm += __shfl_xor(sm, off); qs += __shfl_xor(qs, off);
  }
  __shared__ float rs[4], rq[4];
  const int w = tid >> 6;
  if ((tid & 63) == 0){ rs[w] = sm; rq[w] = qs; }
  __syncthreads();
  sm = rs[0]+rs[1]+rs[2]+rs[3];
  qs = rq[0]+rq[1]+rq[2]+rq[3];
  const float mu   = sm * (1.0f/2048.0f);
  const float var  = qs * (1.0f/2048.0f) - mu*mu;
  const float rstd = rsqrtf(var + 1e-5f);
  const float4 g0 = *(const float4*)(gam + c0);
  const float4 g1 = *(const float4*)(gam + c0 + 4);
  const float4 b0 = *(const float4*)(bet + c0);
  const float4 b1 = *(const float4*)(bet + c0 + 4);
  float o[8];
  o[0] = (y[0]-mu)*rstd*g0.x + b0.x;  o[1] = (y[1]-mu)*rstd*g0.y + b0.y;
  o[2] = (y[2]-mu)*rstd*g0.z + b0.z;  o[3] = (y[3]-mu)*rstd*g0.w + b0.w;
  o[4] = (y[4]-mu)*rstd*g1.x + b1.x;  o[5] = (y[5]-mu)*rstd*g1.y + b1.y;
  o[6] = (y[6]-mu)*rstd*g1.z + b1.z;  o[7] = (y[7]-mu)*rstd*g1.w + b1.w;
  *(float4*)(outF + base)     = make_float4(o[0], o[1], o[2], o[3]);
  *(float4*)(outF + base + 4) = make_float4(o[4], o[5], o[6], o[7]);
  if constexpr (WB){
    uint4 ob;
    ob.x = pack2(o[0], o[1]); ob.y = pack2(o[2], o[3]);
    ob.z = pack2(o[4], o[5]); ob.w = pack2(o[6], o[7]);
    *(uint4*)&outB[base] = ob;
  }
}

// ---------------------------------------------------------------------------
extern "C" void kernel_launch(void* const* d_in, const int* in_sizes, int n_in,
                              void* d_out, int out_size, void* d_ws, size_t ws_size,
                              hipStream_t stream)
{
  const float* seq   = (const float*)d_in[0];
  const float* emb_W = (const float*)d_in[1];
  const float* emb_b = (const float*)d_in[2];
  const float* Wq = (const float*)d_in[3];  const float* bq = (const float*)d_in[4];
  const float* Wk = (const float*)d_in[5];  const float* bk = (const float*)d_in[6];
  const float* Wv = (const float*)d_in[7];  const float* bv = (const float*)d_in[8];
  const float* Wo = (const float*)d_in[9];  const float* bo = (const float*)d_in[10];
  const float* ln_g = (const float*)d_in[11]; const float* ln_b = (const float*)d_in[12];
  const float* W1 = (const float*)d_in[13]; const float* b1 = (const float*)d_in[14];
  const float* W2 = (const float*)d_in[15]; const float* b2 = (const float*)d_in[16];

  char* ws = (char*)d_ws;
  size_t off = 0;
  auto take = [&](size_t bytes) -> void* {
    void* p = ws + off;
    off += (bytes + 255) & ~(size_t)255;
    return p;
  };
  bf16_t* seqB = (bf16_t*)take((size_t)SEQL*DM*2);
  float*  X    = (float*) take((size_t)SEQL*DM*4);
  bf16_t* XB   = (bf16_t*)take((size_t)SEQL*DM*2);
  bf16_t* Qf   = (bf16_t*)take((size_t)SEQL*DM*2);
  bf16_t* Kf   = (bf16_t*)take((size_t)SEQL*DM*2);
  bf16_t* Qhd  = (bf16_t*)take((size_t)SEQL*DM*2);
  bf16_t* Khd  = (bf16_t*)take((size_t)SEQL*DM*2);
  bf16_t* Vt   = (bf16_t*)take((size_t)SEQL*DM*2);
  bf16_t* Afl  = (bf16_t*)take((size_t)SEQL*DM*2);
  float*  Pp   = (float*) take((size_t)8*SEQL*DM*4);  // split-K partials (32 MB)
  float*  Xa   = (float*) take((size_t)SEQL*DM*4);
  bf16_t* XaB  = (bf16_t*)take((size_t)SEQL*DM*2);
  bf16_t* Hb   = (bf16_t*)take((size_t)SEQL*FFH*2);
  (void)ws_size; (void)in_sizes; (void)n_in; (void)out_size;

  // sequence fp32 -> bf16
  cvt_bf16<<<dim3(SEQL*DM/1024), 256, 0, stream>>>(seq, seqB);

  // embedding (split-K x8, 1024 blocks) + posenc reduce
  gemmF<E_PART,0,64><<<dim3(1024), 256, 0, stream>>>(seqB, emb_W, nullptr, nullptr,
      nullptr, nullptr, nullptr, Pp, nullptr, nullptr, nullptr, 16, DM, DM, 256);
  reduce_pos<8><<<SEQL, 256, 0, stream>>>(Pp, emb_b, X, XB);

  // fused QKV (BM=32, 768 blocks)
  gemmF<E_QKV,0,32><<<dim3(768), 256, 0, stream>>>(XB, Wq, Wk, Wv,
      bq, bk, bv, nullptr, Qf, Kf, Vt, 48, DM, DM, DM);
  permute_qk<<<dim3(SEQL,2), 256, 0, stream>>>(Qf, Kf, Qhd, Khd);

  // attention
  attn_kernel<<<dim3(16,16), 256, 0, stream>>>(Qhd, Khd, Vt, Afl);

  // output projection (split-K x8, k-permuted Wo) + residual + LN1
  gemmF<E_PART,1,64><<<dim3(1024), 256, 0, stream>>>(Afl, Wo, nullptr, nullptr,
      nullptr, nullptr, nullptr, Pp, nullptr, nullptr, nullptr, 16, DM, DM, 256);
  reduce_ln<8,1><<<SEQL, 256, 0, stream>>>(Pp, bo, X, ln_g, ln_b, Xa, XaB);

  // FFN1 (BM=32, 1024 blocks)
  gemmF<E_FFN1,0,32><<<dim3(1024), 256, 0, stream>>>(XaB, W1, nullptr, nullptr,
      b1, nullptr, nullptr, nullptr, Hb, nullptr, nullptr, 64, FFH, DM, DM);

  // FFN2 (split-K x8, Kc=1024) + residual + LN2 -> out
  gemmF<E_PART,0,64><<<dim3(1024), 256, 0, stream>>>(Hb, W2, nullptr, nullptr,
      nullptr, nullptr, nullptr, Pp, nullptr, nullptr, nullptr, 16, DM, FFH, 1024);
  reduce_ln<8,0><<<SEQL, 256, 0, stream>>>(Pp, b2, Xa, ln_g, ln_b, (float*)d_out, nullptr);
}

// Round 8
// 239.008 us; speedup vs baseline: 1.1780x; 1.1594x over previous
//
#include <hip/hip_runtime.h>
#include <hip/hip_bf16.h>

// ---------------------------------------------------------------------------
// TransformerEncoder forward on MI355X (gfx950). Round 7:
//   - Streaming fp32->bf16 weight cvt pass (NO transpose, fully coalesced).
//   - GEMM B-staging via global_load_lds with PRE-SWIZZLED per-lane global
//     source -> LDS lands in the tr_b16 subtiled layout (rounds 5/6 verified).
//     K-loop has zero conversion VALU and zero conflicted LDS writes.
//   - BK=64, simple 2-phase pipeline (stage next || compute cur, 1 barrier).
// ---------------------------------------------------------------------------

typedef __bf16 bf16_t;
typedef __bf16 bf16x4 __attribute__((ext_vector_type(4)));
typedef __bf16 bf16x8 __attribute__((ext_vector_type(8)));
typedef float  f32x4  __attribute__((ext_vector_type(4)));

#define SEQL 512
#define DM   2048
#define FFH  8192
#define NH   16
#define DHD  128
#define PST  ((size_t)SEQL*DM)   // partial-slice stride

__device__ __forceinline__ unsigned short bfbits(float f){
  bf16_t h = (bf16_t)f;
  return __builtin_bit_cast(unsigned short, h);
}
__device__ __forceinline__ unsigned int pack2(float a, float b){
  return (unsigned int)bfbits(a) | ((unsigned int)bfbits(b) << 16);
}

__device__ __forceinline__ void gll16(const bf16_t* g, bf16_t* l){
  __builtin_amdgcn_global_load_lds(
      (const __attribute__((address_space(1))) void*)g,
      (__attribute__((address_space(3))) void*)l, 16, 0, 0);
}
__device__ __forceinline__ unsigned lds_off(const void* p){
  return (unsigned)(uintptr_t)(const __attribute__((address_space(3))) void*)p;
}

// ---------------------------------------------------------------------------
// Streaming fp32 -> bf16 convert, 8 segments (seq + 7 weights), layout kept.
// Each block converts 2048 contiguous floats (all segment sizes are multiples).
struct CvtSeg { const float* src; bf16_t* dst; int base; };
struct CvtArgs { CvtSeg s[8]; };

__global__ __launch_bounds__(256)
void cvt_all(CvtArgs a){
  const int b = blockIdx.x;
  int i = 0;
#pragma unroll
  for (int j = 1; j < 8; ++j) if (b >= a.s[j].base) i = j;
  const size_t off = ((size_t)(b - a.s[i].base) * 2048) + threadIdx.x * 8;
  const float4 v0 = *(const float4*)(a.s[i].src + off);
  const float4 v1 = *(const float4*)(a.s[i].src + off + 4);
  uint4 o;
  o.x = pack2(v0.x, v0.y); o.y = pack2(v0.z, v0.w);
  o.z = pack2(v1.x, v1.y); o.w = pack2(v1.z, v1.w);
  *(uint4*)(a.s[i].dst + off) = o;
}

// ---------------------------------------------------------------------------
// GEMM: C[512][N] = A[512][K](bf16) @ WB[K][N](bf16, HW-transposed via tr_b16).
// BM x 128 tile, BK=64, 256 threads, 4 waves.
//   BM=64: wave -> 32m x 64n (NF=4). BM=32: wave -> 32m x 32n (NF=2).
// B LDS per 32k x 128n half-tile (8 KB): nf-th 16-col group at nf*1024,
//   byte(k,nc) = (k>>2)*128 + (k&3)*32 + nc*2. Staged by gll16 with per-lane
//   source: lane l of wave w, pass p: k_l=(l>>3)*4+((l>>1)&3),
//   col=(p*4+w)*16+8*(l&1) -> dest linear (p*256+tid)*16B. tr-read lane(c,g):
//   addr = nf*1024 + g*256 + c*8 (+offset:128) -> W[8g+j][16nf+c].
// A LDS [BM][64] with slot swizzle s^=(row&7), pre-swizzled at global source.
constexpr int E_PART = 0;  // fp32 partial (no bias) -> outF + zt*PST
constexpr int E_QKV  = 1;  // [0,2k)->Qf flat, [2k,4k)->Kf flat, rest->Vt[h][d][key]
constexpr int E_FFN1 = 2;  // bias + gelu -> bf16 [512][FFH]

template<int EPI, int PERM, int BM>
__global__ __launch_bounds__(256, (BM == 64) ? 3 : 4)
void gemmT(const bf16_t* __restrict__ A,
           const bf16_t* __restrict__ B0, const bf16_t* __restrict__ B1,
           const bf16_t* __restrict__ B2,
           const float* __restrict__ b0p, const float* __restrict__ b1p,
           const float* __restrict__ b2p,
           float* __restrict__ outF, bf16_t* __restrict__ o0,
           bf16_t* __restrict__ o1, bf16_t* __restrict__ o2,
           int nn, int Nw, int K, int Kc)
{
  constexpr int NF    = (BM == 64) ? 4 : 2;
  constexpr int APASS = BM / 32;
  constexpr int MTM   = (BM == 64) ? 7 : 15;
  constexpr int MTS   = (BM == 64) ? 3 : 4;
  __shared__ bf16_t sA[2][BM*64];
  __shared__ bf16_t sB[2][128*64];
  const int tid  = threadIdx.x;
  const int lane = tid & 63, w = tid >> 6;
  const int wr4 = (BM == 64) ? (w >> 1) : 0;
  const int wc  = (BM == 64) ? (w & 1)  : w;
  const int c = lane & 15, g = lane >> 4;

  // grid decode (XCD swizzle, m-fastest)
  const int nwg = gridDim.x, cpx = nwg >> 3;
  const int sblk = (blockIdx.x & 7) * cpx + (blockIdx.x >> 3);
  const int mt = sblk & MTM, q2 = sblk >> MTS;
  const int nt = q2 % nn, zt = q2 / nn;
  const int m0 = mt * BM, k0 = zt * Kc;

  // weight select (QKV: three separate [2048][2048] sources)
  const bf16_t* Bsel = B0; int nb0 = nt * 128;
  if constexpr (EPI == E_QKV){
    if (nt >= 32){ Bsel = B2; nb0 = (nt - 32) * 128; }
    else if (nt >= 16){ Bsel = B1; nb0 = (nt - 16) * 128; }
  }

  // A staging: pass pa covers rows pa*32 + w*8 + (lane>>3); slot = lane&7,
  // source col pre-swizzled by row&7 (= lane>>3 here).
  const int arow = tid >> 3;
  const int acol = (((tid & 7) ^ ((tid >> 3) & 7)) << 3);
  const bf16_t* Aps[APASS];
#pragma unroll
  for (int pa = 0; pa < APASS; ++pa)
    Aps[pa] = A + (size_t)(m0 + pa*32 + arow) * K + k0 + acol;

  // B staging: per-lane pre-swizzled source
  const int klB  = (lane >> 3) * 4 + ((lane >> 1) & 3);      // 0..31 within half
  const int colB = nb0 + w*16 + (lane & 1)*8;                // + p*64 per pass
  const bf16_t* Bph[2];
  if constexpr (!PERM){
#pragma unroll
    for (int h = 0; h < 2; ++h)
      Bph[h] = Bsel + (size_t)(k0 + h*32 + klB) * Nw + colB;
  }

  const unsigned sBbase[2] = { lds_off(&sB[0][0]), lds_off(&sB[1][0]) };
  const unsigned trLane = (unsigned)(g*256 + c*8);

  f32x4 acc[2][NF] = {};
  const int nk = Kc >> 6;

#define STAGE(bf, kt) {                                                     \
    _Pragma("unroll")                                                       \
    for (int pa = 0; pa < APASS; ++pa)                                      \
      gll16(Aps[pa] + (size_t)(kt)*64, &sA[bf][(pa*256 + tid)*8]);          \
    _Pragma("unroll")                                                       \
    for (int h = 0; h < 2; ++h)                                             \
      _Pragma("unroll")                                                     \
      for (int p = 0; p < 2; ++p){                                          \
        const bf16_t* src;                                                  \
        if constexpr (PERM){                                                \
          const int kr = k0 + (kt)*64 + h*32 + klB;                         \
          const int krow = ((kr & 127) << 4) + (kr >> 7);                   \
          src = Bsel + (size_t)krow * Nw + colB + p*64;                     \
        } else {                                                            \
          src = Bph[h] + (size_t)(kt)*64*Nw + p*64;                         \
        }                                                                   \
        gll16(src, &sB[bf][h*4096 + (p*256 + tid)*8]);                      \
      } }

#define COMPUTE(PB) {                                                       \
    bf16x8 af[2][2]; bf16x8 bq[NF][2];                                      \
    _Pragma("unroll")                                                       \
    for (int m = 0; m < 2; ++m)                                             \
      _Pragma("unroll")                                                     \
      for (int ks = 0; ks < 2; ++ks){                                       \
        const int r = wr4*32 + m*16 + c;                                    \
        af[m][ks] = *(const bf16x8*)&sA[PB][r*64 + (((ks*4+g) ^ (r&7))<<3)];\
      }                                                                     \
    { const unsigned base = sBbase[PB] + (unsigned)(wc*NF*1024) + trLane;   \
      _Pragma("unroll")                                                     \
      for (int n = 0; n < NF; ++n)                                          \
        _Pragma("unroll")                                                   \
        for (int ks = 0; ks < 2; ++ks){                                     \
          bf16x4 r0, r1;                                                    \
          const unsigned a2 = base + (unsigned)(n*1024 + ks*8192);          \
          asm volatile("ds_read_b64_tr_b16 %0, %1" : "=v"(r0) : "v"(a2));   \
          asm volatile("ds_read_b64_tr_b16 %0, %1 offset:128" : "=v"(r1) : "v"(a2)); \
          bq[n][ks] = __builtin_shufflevector(r0, r1, 0,1,2,3,4,5,6,7);     \
        } }                                                                 \
    asm volatile("s_waitcnt lgkmcnt(0)" ::: "memory");                      \
    __builtin_amdgcn_sched_barrier(0);                                      \
    _Pragma("unroll")                                                       \
    for (int m = 0; m < 2; ++m)                                             \
      _Pragma("unroll")                                                     \
      for (int n = 0; n < NF; ++n)                                          \
        _Pragma("unroll")                                                   \
        for (int ks = 0; ks < 2; ++ks)                                      \
          acc[m][n] = __builtin_amdgcn_mfma_f32_16x16x32_bf16(af[m][ks], bq[n][ks], acc[m][n], 0,0,0); }

  STAGE(0, 0);
  asm volatile("s_waitcnt vmcnt(0)" ::: "memory");
  __builtin_amdgcn_s_barrier();
  __builtin_amdgcn_sched_barrier(0);

  int buf = 0;
  for (int kt = 0; kt < nk; ++kt){
    if (kt + 1 < nk){ STAGE(buf ^ 1, kt + 1); }
    COMPUTE(buf);
    asm volatile("s_waitcnt vmcnt(0)" ::: "memory");
    __builtin_amdgcn_s_barrier();
    __builtin_amdgcn_sched_barrier(0);
    buf ^= 1;
  }
#undef STAGE
#undef COMPUTE

  // epilogue: row = m0 + wr4*32 + m*16 + 4g + rr, col = nt*128 + wc*(NF*16) + n*16 + c
#pragma unroll
  for (int n = 0; n < NF; ++n){
    const int col = nt*128 + wc*(NF*16) + n*16 + c;
#pragma unroll
    for (int m = 0; m < 2; ++m){
      const int row0 = m0 + wr4*32 + m*16 + 4*g;
      const f32x4 a4 = acc[m][n];
      if constexpr (EPI == E_PART){
        float* dst = outF + (size_t)zt * PST;
#pragma unroll
        for (int rr = 0; rr < 4; ++rr)
          dst[(size_t)(row0+rr)*DM + col] = a4[rr];
      } else if constexpr (EPI == E_QKV){
        if (col < DM){
          const float bv = b0p[col];
#pragma unroll
          for (int rr = 0; rr < 4; ++rr)
            o0[(size_t)(row0+rr)*DM + col] = (bf16_t)(a4[rr] + bv);
        } else if (col < 2*DM){
          const int cc = col - DM;
          const float bv = b1p[cc];
#pragma unroll
          for (int rr = 0; rr < 4; ++rr)
            o1[(size_t)(row0+rr)*DM + cc] = (bf16_t)(a4[rr] + bv);
        } else {
          const int cc = col - 2*DM;
          const float bv = b2p[cc];
          const int hh = cc & 15, dd = cc >> 4;
          unsigned short us[4];
#pragma unroll
          for (int rr = 0; rr < 4; ++rr) us[rr] = bfbits(a4[rr] + bv);
          *(ushort4*)&o2[(size_t)(hh*DHD + dd)*SEQL + row0] =
              make_ushort4(us[0], us[1], us[2], us[3]);
        }
      } else if constexpr (EPI == E_FFN1){
        const float bv = b0p[col];
#pragma unroll
        for (int rr = 0; rr < 4; ++rr){
          const float v = a4[rr] + bv;
          const float z = v * (v*v*0.044715f + 1.0f) * 1.5957691216f;
          const float gg = v / (1.0f + __expf(-z));
          o0[(size_t)(row0+rr)*FFH + col] = (bf16_t)gg;
        }
      }
    }
  }
}

// ---------------------------------------------------------------------------
// Gather Q/K flat [row][16d+h] -> head layout [h][row][d] (pure bit-move).
__global__ __launch_bounds__(256)
void permute_qk(const bf16_t* __restrict__ Qf, const bf16_t* __restrict__ Kf,
                bf16_t* __restrict__ Qhd, bf16_t* __restrict__ Khd)
{
  const int row = blockIdx.x, which = blockIdx.y, tid = threadIdx.x;
  const bf16_t* src = (which ? Kf : Qf) + (size_t)row * DM;
  bf16_t* dst = which ? Khd : Qhd;
  const int hh = tid >> 4, d0 = (tid & 15) * 8;
  unsigned short us[8];
#pragma unroll
  for (int j = 0; j < 8; ++j)
    us[j] = __builtin_bit_cast(unsigned short, src[(d0 + j)*NH + hh]);
  uint4 o;
  o.x = (unsigned)us[0] | ((unsigned)us[1] << 16);
  o.y = (unsigned)us[2] | ((unsigned)us[3] << 16);
  o.z = (unsigned)us[4] | ((unsigned)us[5] << 16);
  o.w = (unsigned)us[6] | ((unsigned)us[7] << 16);
  *(uint4*)&dst[(size_t)hh*(SEQL*DHD) + (size_t)row*DHD + d0] = o;
}

// ---------------------------------------------------------------------------
// Attention: one block per (32 q-rows, head). Full softmax over 512 keys.
// Qh/Kh: [h][row][d]  Vt: [h][d][key]  Aout: [row][h*128+d] bf16
__global__ __launch_bounds__(256)
void attn_kernel(const bf16_t* __restrict__ Qh, const bf16_t* __restrict__ Kh,
                 const bf16_t* __restrict__ Vt, bf16_t* __restrict__ Aout)
{
  __shared__ bf16_t Pl[32*512];
  __shared__ float redm[4][32];
  __shared__ float reds[4][32];
  const int tid = threadIdx.x;
  const int lane = tid & 63, w = tid >> 6;
  const int c = lane & 15, g = lane >> 4;
  const int h = blockIdx.y;
  const int rb = blockIdx.x * 32;
  const bf16_t* Qb = Qh + (size_t)h * (SEQL*DHD);
  const bf16_t* Kb = Kh + (size_t)h * (SEQL*DHD);
  const bf16_t* Vb = Vt + (size_t)h * (SEQL*DHD);

  bf16x8 qf[2][4];
#pragma unroll
  for (int a = 0; a < 2; ++a)
#pragma unroll
    for (int ks = 0; ks < 4; ++ks)
      qf[a][ks] = *(const bf16x8*)(Qb + (size_t)(rb + a*16 + c)*DHD + ks*32 + g*8);

  f32x4 s[2][8] = {};
#pragma unroll
  for (int ks = 0; ks < 4; ++ks)
#pragma unroll
    for (int b = 0; b < 8; ++b){
      const bf16x8 kf = *(const bf16x8*)(Kb + (size_t)(w*128 + b*16 + c)*DHD + ks*32 + g*8);
      s[0][b] = __builtin_amdgcn_mfma_f32_16x16x32_bf16(qf[0][ks], kf, s[0][b], 0,0,0);
      s[1][b] = __builtin_amdgcn_mfma_f32_16x16x32_bf16(qf[1][ks], kf, s[1][b], 0,0,0);
    }
  // 1/sqrt(2048) score scale
#pragma unroll
  for (int a = 0; a < 2; ++a)
#pragma unroll
    for (int b = 0; b < 8; ++b)
#pragma unroll
      for (int rr = 0; rr < 4; ++rr) s[a][b][rr] *= 0.022097086912079612f;

  float mx[2][4], sm[2][4], inv[2][4];
#pragma unroll
  for (int a = 0; a < 2; ++a)
#pragma unroll
    for (int rr = 0; rr < 4; ++rr){
      float m = s[a][0][rr];
#pragma unroll
      for (int b = 1; b < 8; ++b) m = fmaxf(m, s[a][b][rr]);
#pragma unroll
      for (int off = 1; off < 16; off <<= 1) m = fmaxf(m, __shfl_xor(m, off));
      mx[a][rr] = m;
    }
  if (c == 0)
#pragma unroll
    for (int a = 0; a < 2; ++a)
#pragma unroll
      for (int rr = 0; rr < 4; ++rr) redm[w][a*16 + 4*g + rr] = mx[a][rr];
  __syncthreads();
#pragma unroll
  for (int a = 0; a < 2; ++a)
#pragma unroll
    for (int rr = 0; rr < 4; ++rr){
      const int lr = a*16 + 4*g + rr;
      mx[a][rr] = fmaxf(fmaxf(redm[0][lr], redm[1][lr]), fmaxf(redm[2][lr], redm[3][lr]));
      sm[a][rr] = 0.f;
    }
#pragma unroll
  for (int a = 0; a < 2; ++a)
#pragma unroll
    for (int b = 0; b < 8; ++b)
#pragma unroll
      for (int rr = 0; rr < 4; ++rr){
        const float p = __expf(s[a][b][rr] - mx[a][rr]);
        s[a][b][rr] = p;
        sm[a][rr] += p;
      }
#pragma unroll
  for (int a = 0; a < 2; ++a)
#pragma unroll
    for (int rr = 0; rr < 4; ++rr){
#pragma unroll
      for (int off = 1; off < 16; off <<= 1) sm[a][rr] += __shfl_xor(sm[a][rr], off);
    }
  if (c == 0)
#pragma unroll
    for (int a = 0; a < 2; ++a)
#pragma unroll
      for (int rr = 0; rr < 4; ++rr) reds[w][a*16 + 4*g + rr] = sm[a][rr];
  __syncthreads();
#pragma unroll
  for (int a = 0; a < 2; ++a)
#pragma unroll
    for (int rr = 0; rr < 4; ++rr){
      const int lr = a*16 + 4*g + rr;
      inv[a][rr] = 1.0f / (reds[0][lr] + reds[1][lr] + reds[2][lr] + reds[3][lr]);
    }

#pragma unroll
  for (int a = 0; a < 2; ++a)
#pragma unroll
    for (int b = 0; b < 8; ++b)
#pragma unroll
      for (int rr = 0; rr < 4; ++rr){
        const int lr  = a*16 + 4*g + rr;
        const int key = w*128 + b*16 + c;
        const int slot = (key >> 3) ^ (lr & 7);
        Pl[lr*512 + slot*8 + (key & 7)] = (bf16_t)(s[a][b][rr] * inv[a][rr]);
      }
  __syncthreads();

  f32x4 o[2][2] = {};
  const int dw = w * 32;
#pragma unroll
  for (int kst = 0; kst < 16; ++kst){
    bf16x8 pa2[2];
#pragma unroll
    for (int a = 0; a < 2; ++a){
      const int r = a*16 + c;
      const int slot = (kst*4 + g) ^ (r & 7);
      pa2[a] = *(const bf16x8*)&Pl[r*512 + slot*8];
    }
#pragma unroll
    for (int db = 0; db < 2; ++db){
      const bf16x8 vf = *(const bf16x8*)(Vb + (size_t)(dw + db*16 + c)*SEQL + kst*32 + g*8);
      o[0][db] = __builtin_amdgcn_mfma_f32_16x16x32_bf16(pa2[0], vf, o[0][db], 0,0,0);
      o[1][db] = __builtin_amdgcn_mfma_f32_16x16x32_bf16(pa2[1], vf, o[1][db], 0,0,0);
    }
  }
#pragma unroll
  for (int a = 0; a < 2; ++a)
#pragma unroll
    for (int db = 0; db < 2; ++db)
#pragma unroll
      for (int rr = 0; rr < 4; ++rr){
        const int row  = rb + a*16 + 4*g + rr;
        const int col2 = h*DHD + dw + db*16 + c;
        Aout[(size_t)row*DM + col2] = (bf16_t)o[a][db][rr];
      }
}

// ---------------------------------------------------------------------------
// reduce S split-K partials + bias + positional encoding -> X fp32 + XB bf16
template<int S>
__global__ __launch_bounds__(256)
void reduce_pos(const float* __restrict__ P, const float* __restrict__ bias,
                float* __restrict__ X, bf16_t* __restrict__ XB)
{
  const int row = blockIdx.x, c0 = threadIdx.x * 8;
  const size_t base = (size_t)row * DM + c0;
  float y[8];
#pragma unroll
  for (int j = 0; j < 8; ++j) y[j] = bias[c0 + j];
#pragma unroll
  for (int s = 0; s < S; ++s){
    const float4 v0 = *(const float4*)(P + s*PST + base);
    const float4 v1 = *(const float4*)(P + s*PST + base + 4);
    y[0]+=v0.x; y[1]+=v0.y; y[2]+=v0.z; y[3]+=v0.w;
    y[4]+=v1.x; y[5]+=v1.y; y[6]+=v1.z; y[7]+=v1.w;
  }
#pragma unroll
  for (int j = 0; j < 8; ++j){
    const int col = c0 + j;
    const float fr  = 1e-4f * __expf(-(float)(col >> 1) * (1.0f/1024.0f));
    const float ang = (float)row * fr;
    y[j] += (col & 1) ? __cosf(ang) : __sinf(ang);
  }
  *(float4*)(X + base)     = make_float4(y[0], y[1], y[2], y[3]);
  *(float4*)(X + base + 4) = make_float4(y[4], y[5], y[6], y[7]);
  uint4 ob;
  ob.x = pack2(y[0], y[1]); ob.y = pack2(y[2], y[3]);
  ob.z = pack2(y[4], y[5]); ob.w = pack2(y[6], y[7]);
  *(uint4*)&XB[base] = ob;
}

// ---------------------------------------------------------------------------
// reduce S split-K partials + bias + residual, then row-LayerNorm(2048).
template<int S, int WB>
__global__ __launch_bounds__(256)
void reduce_ln(const float* __restrict__ P, const float* __restrict__ bias,
               const float* __restrict__ resid, const float* __restrict__ gam,
               const float* __restrict__ bet, float* __restrict__ outF,
               bf16_t* __restrict__ outB)
{
  const int row = blockIdx.x, tid = threadIdx.x, c0 = tid * 8;
  const size_t base = (size_t)row * DM + c0;
  float y[8];
  {
    const float4 r0 = *(const float4*)(resid + base);
    const float4 r1 = *(const float4*)(resid + base + 4);
    y[0]=r0.x; y[1]=r0.y; y[2]=r0.z; y[3]=r0.w;
    y[4]=r1.x; y[5]=r1.y; y[6]=r1.z; y[7]=r1.w;
  }
#pragma unroll
  for (int j = 0; j < 8; ++j) y[j] += bias[c0 + j];
#pragma unroll
  for (int s = 0; s < S; ++s){
    const float4 v0 = *(const float4*)(P + s*PST + base);
    const float4 v1 = *(const float4*)(P + s*PST + base + 4);
    y[0]+=v0.x; y[1]+=v0.y; y[2]+=v0.z; y[3]+=v0.w;
    y[4]+=v1.x; y[5]+=v1.y; y[6]+=v1.z; y[7]+=v1.w;
  }
  float sm = 0.f, qs = 0.f;
#pragma unroll
  for (int j = 0; j < 8; ++j){ sm += y[j]; qs += y[j]*y[j]; }
#pragma unroll
  for (int off = 32; off >= 1; off >>= 1){
    sm += __shfl_xor(sm, off); qs += __shfl_xor(qs, off);
  }
  __shared__ float rs[4], rq[4];
  const int w = tid >> 6;
  if ((tid & 63) == 0){ rs[w] = sm; rq[w] = qs; }
  __syncthreads();
  sm = rs[0]+rs[1]+rs[2]+rs[3];
  qs = rq[0]+rq[1]+rq[2]+rq[3];
  const float mu   = sm * (1.0f/2048.0f);
  const float var  = qs * (1.0f/2048.0f) - mu*mu;
  const float rstd = rsqrtf(var + 1e-5f);
  const float4 g0 = *(const float4*)(gam + c0);
  const float4 g1 = *(const float4*)(gam + c0 + 4);
  const float4 b0 = *(const float4*)(bet + c0);
  const float4 b1 = *(const float4*)(bet + c0 + 4);
  float o[8];
  o[0] = (y[0]-mu)*rstd*g0.x + b0.x;  o[1] = (y[1]-mu)*rstd*g0.y + b0.y;
  o[2] = (y[2]-mu)*rstd*g0.z + b0.z;  o[3] = (y[3]-mu)*rstd*g0.w + b0.w;
  o[4] = (y[4]-mu)*rstd*g1.x + b1.x;  o[5] = (y[5]-mu)*rstd*g1.y + b1.y;
  o[6] = (y[6]-mu)*rstd*g1.z + b1.z;  o[7] = (y[7]-mu)*rstd*g1.w + b1.w;
  *(float4*)(outF + base)     = make_float4(o[0], o[1], o[2], o[3]);
  *(float4*)(outF + base + 4) = make_float4(o[4], o[5], o[6], o[7]);
  if constexpr (WB){
    uint4 ob;
    ob.x = pack2(o[0], o[1]); ob.y = pack2(o[2], o[3]);
    ob.z = pack2(o[4], o[5]); ob.w = pack2(o[6], o[7]);
    *(uint4*)&outB[base] = ob;
  }
}

// ---------------------------------------------------------------------------
extern "C" void kernel_launch(void* const* d_in, const int* in_sizes, int n_in,
                              void* d_out, int out_size, void* d_ws, size_t ws_size,
                              hipStream_t stream)
{
  const float* seq   = (const float*)d_in[0];
  const float* emb_W = (const float*)d_in[1];
  const float* emb_b = (const float*)d_in[2];
  const float* Wq = (const float*)d_in[3];  const float* bq = (const float*)d_in[4];
  const float* Wk = (const float*)d_in[5];  const float* bk = (const float*)d_in[6];
  const float* Wv = (const float*)d_in[7];  const float* bv = (const float*)d_in[8];
  const float* Wo = (const float*)d_in[9];  const float* bo = (const float*)d_in[10];
  const float* ln_g = (const float*)d_in[11]; const float* ln_b = (const float*)d_in[12];
  const float* W1 = (const float*)d_in[13]; const float* b1 = (const float*)d_in[14];
  const float* W2 = (const float*)d_in[15]; const float* b2 = (const float*)d_in[16];

  char* ws = (char*)d_ws;
  size_t off = 0;
  auto take = [&](size_t bytes) -> void* {
    void* p = ws + off;
    off += (bytes + 255) & ~(size_t)255;
    return p;
  };
  bf16_t* seqB = (bf16_t*)take((size_t)SEQL*DM*2);
  bf16_t* WeB  = (bf16_t*)take((size_t)DM*DM*2);
  bf16_t* WqB  = (bf16_t*)take((size_t)DM*DM*2);
  bf16_t* WkB  = (bf16_t*)take((size_t)DM*DM*2);
  bf16_t* WvB  = (bf16_t*)take((size_t)DM*DM*2);
  bf16_t* WoB  = (bf16_t*)take((size_t)DM*DM*2);
  bf16_t* W1B  = (bf16_t*)take((size_t)DM*FFH*2);
  bf16_t* W2B  = (bf16_t*)take((size_t)FFH*DM*2);
  float*  X    = (float*) take((size_t)SEQL*DM*4);
  bf16_t* XB   = (bf16_t*)take((size_t)SEQL*DM*2);
  bf16_t* Qf   = (bf16_t*)take((size_t)SEQL*DM*2);
  bf16_t* Kf   = (bf16_t*)take((size_t)SEQL*DM*2);
  bf16_t* Qhd  = (bf16_t*)take((size_t)SEQL*DM*2);
  bf16_t* Khd  = (bf16_t*)take((size_t)SEQL*DM*2);
  bf16_t* Vt   = (bf16_t*)take((size_t)SEQL*DM*2);
  bf16_t* Afl  = (bf16_t*)take((size_t)SEQL*DM*2);
  float*  Pp   = (float*) take((size_t)8*SEQL*DM*4);  // split-K partials (32 MB)
  float*  Xa   = (float*) take((size_t)SEQL*DM*4);
  bf16_t* XaB  = (bf16_t*)take((size_t)SEQL*DM*2);
  bf16_t* Hb   = (bf16_t*)take((size_t)SEQL*FFH*2);
  (void)ws_size; (void)in_sizes; (void)n_in; (void)out_size;

  // streaming cvt: seq + all 7 weights, layout preserved
  // block counts: seq 512, 2048 each for 2048x2048, 8192 for the FFN weights
  CvtArgs ca;
  ca.s[0] = { seq,   seqB,     0 };
  ca.s[1] = { emb_W, WeB,    512 };
  ca.s[2] = { Wq,    WqB,   2560 };
  ca.s[3] = { Wk,    WkB,   4608 };
  ca.s[4] = { Wv,    WvB,   6656 };
  ca.s[5] = { Wo,    WoB,   8704 };
  ca.s[6] = { W1,    W1B,  10752 };
  ca.s[7] = { W2,    W2B,  18944 };
  cvt_all<<<dim3(27136), 256, 0, stream>>>(ca);

  // embedding (split-K x4, grid 512) + posenc reduce
  gemmT<E_PART,0,64><<<dim3(512), 256, 0, stream>>>(seqB, WeB, nullptr, nullptr,
      nullptr, nullptr, nullptr, Pp, nullptr, nullptr, nullptr, 16, DM, DM, 512);
  reduce_pos<4><<<SEQL, 256, 0, stream>>>(Pp, emb_b, X, XB);

  // fused QKV (BM=32, grid 768)
  gemmT<E_QKV,0,32><<<dim3(768), 256, 0, stream>>>(XB, WqB, WkB, WvB,
      bq, bk, bv, nullptr, Qf, Kf, Vt, 48, DM, DM, DM);
  permute_qk<<<dim3(SEQL,2), 256, 0, stream>>>(Qf, Kf, Qhd, Khd);

  // attention
  attn_kernel<<<dim3(16,16), 256, 0, stream>>>(Qhd, Khd, Vt, Afl);

  // output projection (split-K x4, k-permuted Wo rows) + residual + LN1
  gemmT<E_PART,1,64><<<dim3(512), 256, 0, stream>>>(Afl, WoB, nullptr, nullptr,
      nullptr, nullptr, nullptr, Pp, nullptr, nullptr, nullptr, 16, DM, DM, 512);
  reduce_ln<4,1><<<SEQL, 256, 0, stream>>>(Pp, bo, X, ln_g, ln_b, Xa, XaB);

  // FFN1 (BM=32, grid 1024)
  gemmT<E_FFN1,0,32><<<dim3(1024), 256, 0, stream>>>(XaB, W1B, nullptr, nullptr,
      b1, nullptr, nullptr, nullptr, Hb, nullptr, nullptr, 64, FFH, DM, DM);

  // FFN2 (split-K x8, Kc=1024, grid 1024) + residual + LN2 -> out
  gemmT<E_PART,0,64><<<dim3(1024), 256, 0, stream>>>(Hb, W2B, nullptr, nullptr,
      nullptr, nullptr, nullptr, Pp, nullptr, nullptr, nullptr, 16, DM, FFH, 1024);
  reduce_ln<8,0><<<SEQL, 256, 0, stream>>>(Pp, b2, Xa, ln_g, ln_b, (float*)d_out, nullptr);
}

// Round 9
// 223.545 us; speedup vs baseline: 1.2595x; 1.0692x over previous
//
#include <hip/hip_runtime.h>
#include <hip/hip_bf16.h>

// ---------------------------------------------------------------------------
// TransformerEncoder forward on MI355X (gfx950). Round 8:
//   - fp32->bf16 weight conversion OVERLAPPED with compute via block
//     specialization: extra blocks appended to the emb-GEMM (converts Wqkv),
//     QKV-GEMM (converts W1) and attention (converts Wo+W2) grids run the
//     streaming cvt and exit. Single stream, dependencies = kernel order.
//   - cvt does 4 chunks/block with 8 loads in flight (round 7 was 2.6 TB/s
//     with 2 loads/thread).
//   - GEMM/attn bodies identical to round 7 (verified).
// ---------------------------------------------------------------------------

typedef __bf16 bf16_t;
typedef __bf16 bf16x4 __attribute__((ext_vector_type(4)));
typedef __bf16 bf16x8 __attribute__((ext_vector_type(8)));
typedef float  f32x4  __attribute__((ext_vector_type(4)));

#define SEQL 512
#define DM   2048
#define FFH  8192
#define NH   16
#define DHD  128
#define PST  ((size_t)SEQL*DM)   // partial-slice stride

__device__ __forceinline__ unsigned short bfbits(float f){
  bf16_t h = (bf16_t)f;
  return __builtin_bit_cast(unsigned short, h);
}
__device__ __forceinline__ unsigned int pack2(float a, float b){
  return (unsigned int)bfbits(a) | ((unsigned int)bfbits(b) << 16);
}

__device__ __forceinline__ void gll16(const bf16_t* g, bf16_t* l){
  __builtin_amdgcn_global_load_lds(
      (const __attribute__((address_space(1))) void*)g,
      (__attribute__((address_space(3))) void*)l, 16, 0, 0);
}
__device__ __forceinline__ unsigned lds_off(const void* p){
  return (unsigned)(uintptr_t)(const __attribute__((address_space(3))) void*)p;
}

// ---------------------------------------------------------------------------
// Streaming fp32 -> bf16 convert. One block = 8192 consecutive floats
// (4 chunks of 2048; 8 loads issued before the 4 stores for MLP).
struct CvtSeg { const float* src; bf16_t* dst; int base; };  // base in 8192-float blocks
struct CvtA3  { CvtSeg s[3]; };

template<int NS>
__device__ __forceinline__ void cvt_block8k(const CvtSeg* segs, int b){
  int i = 0;
#pragma unroll
  for (int j = 1; j < NS; ++j) if (b >= segs[j].base) i = j;
  const float* src = segs[i].src;
  bf16_t* dst = segs[i].dst;
  const size_t off0 = (size_t)(b - segs[i].base) * 8192 + threadIdx.x * 8;
  f32x4 v[8];
#pragma unroll
  for (int it = 0; it < 4; ++it){
    v[2*it]   = *(const f32x4*)(src + off0 + it*2048);
    v[2*it+1] = *(const f32x4*)(src + off0 + it*2048 + 4);
  }
#pragma unroll
  for (int it = 0; it < 4; ++it){
    uint4 o;
    o.x = pack2(v[2*it][0],   v[2*it][1]);
    o.y = pack2(v[2*it][2],   v[2*it][3]);
    o.z = pack2(v[2*it+1][0], v[2*it+1][1]);
    o.w = pack2(v[2*it+1][2], v[2*it+1][3]);
    *(uint4*)(dst + off0 + it*2048) = o;
  }
}

template<int NS>
__global__ __launch_bounds__(256)
void cvt8k(CvtA3 a){ cvt_block8k<NS>(a.s, blockIdx.x); }

// ---------------------------------------------------------------------------
// GEMM: C[512][N] = A[512][K](bf16) @ WB[K][N](bf16, HW-transposed via tr_b16).
// Identical structure to round 7 (verified); blocks >= gemmN run cvt instead.
constexpr int E_PART = 0;  // fp32 partial (no bias) -> outF + zt*PST
constexpr int E_QKV  = 1;  // [0,2k)->Qf flat, [2k,4k)->Kf flat, rest->Vt[h][d][key]
constexpr int E_FFN1 = 2;  // bias + gelu -> bf16 [512][FFH]

template<int EPI, int PERM, int BM, int NCVT>
__global__ __launch_bounds__(256, (BM == 64) ? 3 : 4)
void gemmT(const bf16_t* __restrict__ A,
           const bf16_t* __restrict__ B0, const bf16_t* __restrict__ B1,
           const bf16_t* __restrict__ B2,
           const float* __restrict__ b0p, const float* __restrict__ b1p,
           const float* __restrict__ b2p,
           float* __restrict__ outF, bf16_t* __restrict__ o0,
           bf16_t* __restrict__ o1, bf16_t* __restrict__ o2,
           int nn, int Nw, int K, int Kc, int gemmN, CvtA3 cva)
{
  if constexpr (NCVT > 0){
    if ((int)blockIdx.x >= gemmN){
      cvt_block8k<NCVT>(cva.s, (int)blockIdx.x - gemmN);
      return;
    }
  }
  constexpr int NF    = (BM == 64) ? 4 : 2;
  constexpr int APASS = BM / 32;
  constexpr int MTM   = (BM == 64) ? 7 : 15;
  constexpr int MTS   = (BM == 64) ? 3 : 4;
  __shared__ bf16_t sA[2][BM*64];
  __shared__ bf16_t sB[2][128*64];
  const int tid  = threadIdx.x;
  const int lane = tid & 63, w = tid >> 6;
  const int wr4 = (BM == 64) ? (w >> 1) : 0;
  const int wc  = (BM == 64) ? (w & 1)  : w;
  const int c = lane & 15, g = lane >> 4;

  // grid decode (XCD swizzle, m-fastest) over the gemm sub-grid only
  const int cpx = gemmN >> 3;
  const int sblk = ((int)blockIdx.x & 7) * cpx + ((int)blockIdx.x >> 3);
  const int mt = sblk & MTM, q2 = sblk >> MTS;
  const int nt = q2 % nn, zt = q2 / nn;
  const int m0 = mt * BM, k0 = zt * Kc;

  // weight select (QKV: three separate [2048][2048] sources)
  const bf16_t* Bsel = B0; int nb0 = nt * 128;
  if constexpr (EPI == E_QKV){
    if (nt >= 32){ Bsel = B2; nb0 = (nt - 32) * 128; }
    else if (nt >= 16){ Bsel = B1; nb0 = (nt - 16) * 128; }
  }

  // A staging
  const int arow = tid >> 3;
  const int acol = (((tid & 7) ^ ((tid >> 3) & 7)) << 3);
  const bf16_t* Aps[APASS];
#pragma unroll
  for (int pa = 0; pa < APASS; ++pa)
    Aps[pa] = A + (size_t)(m0 + pa*32 + arow) * K + k0 + acol;

  // B staging: per-lane pre-swizzled source
  const int klB  = (lane >> 3) * 4 + ((lane >> 1) & 3);
  const int colB = nb0 + w*16 + (lane & 1)*8;
  const bf16_t* Bph[2];
  if constexpr (!PERM){
#pragma unroll
    for (int h = 0; h < 2; ++h)
      Bph[h] = Bsel + (size_t)(k0 + h*32 + klB) * Nw + colB;
  }

  const unsigned sBbase[2] = { lds_off(&sB[0][0]), lds_off(&sB[1][0]) };
  const unsigned trLane = (unsigned)(g*256 + c*8);

  f32x4 acc[2][NF] = {};
  const int nk = Kc >> 6;

#define STAGE(bf, kt) {                                                     \
    _Pragma("unroll")                                                       \
    for (int pa = 0; pa < APASS; ++pa)                                      \
      gll16(Aps[pa] + (size_t)(kt)*64, &sA[bf][(pa*256 + tid)*8]);          \
    _Pragma("unroll")                                                       \
    for (int h = 0; h < 2; ++h)                                             \
      _Pragma("unroll")                                                     \
      for (int p = 0; p < 2; ++p){                                          \
        const bf16_t* src;                                                  \
        if constexpr (PERM){                                                \
          const int kr = k0 + (kt)*64 + h*32 + klB;                         \
          const int krow = ((kr & 127) << 4) + (kr >> 7);                   \
          src = Bsel + (size_t)krow * Nw + colB + p*64;                     \
        } else {                                                            \
          src = Bph[h] + (size_t)(kt)*64*Nw + p*64;                         \
        }                                                                   \
        gll16(src, &sB[bf][h*4096 + (p*256 + tid)*8]);                      \
      } }

#define COMPUTE(PB) {                                                       \
    bf16x8 af[2][2]; bf16x8 bq[NF][2];                                      \
    _Pragma("unroll")                                                       \
    for (int m = 0; m < 2; ++m)                                             \
      _Pragma("unroll")                                                     \
      for (int ks = 0; ks < 2; ++ks){                                       \
        const int r = wr4*32 + m*16 + c;                                    \
        af[m][ks] = *(const bf16x8*)&sA[PB][r*64 + (((ks*4+g) ^ (r&7))<<3)];\
      }                                                                     \
    { const unsigned base = sBbase[PB] + (unsigned)(wc*NF*1024) + trLane;   \
      _Pragma("unroll")                                                     \
      for (int n = 0; n < NF; ++n)                                          \
        _Pragma("unroll")                                                   \
        for (int ks = 0; ks < 2; ++ks){                                     \
          bf16x4 r0, r1;                                                    \
          const unsigned a2 = base + (unsigned)(n*1024 + ks*8192);          \
          asm volatile("ds_read_b64_tr_b16 %0, %1" : "=v"(r0) : "v"(a2));   \
          asm volatile("ds_read_b64_tr_b16 %0, %1 offset:128" : "=v"(r1) : "v"(a2)); \
          bq[n][ks] = __builtin_shufflevector(r0, r1, 0,1,2,3,4,5,6,7);     \
        } }                                                                 \
    asm volatile("s_waitcnt lgkmcnt(0)" ::: "memory");                      \
    __builtin_amdgcn_sched_barrier(0);                                      \
    _Pragma("unroll")                                                       \
    for (int m = 0; m < 2; ++m)                                             \
      _Pragma("unroll")                                                     \
      for (int n = 0; n < NF; ++n)                                          \
        _Pragma("unroll")                                                   \
        for (int ks = 0; ks < 2; ++ks)                                      \
          acc[m][n] = __builtin_amdgcn_mfma_f32_16x16x32_bf16(af[m][ks], bq[n][ks], acc[m][n], 0,0,0); }

  STAGE(0, 0);
  asm volatile("s_waitcnt vmcnt(0)" ::: "memory");
  __builtin_amdgcn_s_barrier();
  __builtin_amdgcn_sched_barrier(0);

  int buf = 0;
  for (int kt = 0; kt < nk; ++kt){
    if (kt + 1 < nk){ STAGE(buf ^ 1, kt + 1); }
    COMPUTE(buf);
    asm volatile("s_waitcnt vmcnt(0)" ::: "memory");
    __builtin_amdgcn_s_barrier();
    __builtin_amdgcn_sched_barrier(0);
    buf ^= 1;
  }
#undef STAGE
#undef COMPUTE

  // epilogue
#pragma unroll
  for (int n = 0; n < NF; ++n){
    const int col = nt*128 + wc*(NF*16) + n*16 + c;
#pragma unroll
    for (int m = 0; m < 2; ++m){
      const int row0 = m0 + wr4*32 + m*16 + 4*g;
      const f32x4 a4 = acc[m][n];
      if constexpr (EPI == E_PART){
        float* dst = outF + (size_t)zt * PST;
#pragma unroll
        for (int rr = 0; rr < 4; ++rr)
          dst[(size_t)(row0+rr)*DM + col] = a4[rr];
      } else if constexpr (EPI == E_QKV){
        if (col < DM){
          const float bv = b0p[col];
#pragma unroll
          for (int rr = 0; rr < 4; ++rr)
            o0[(size_t)(row0+rr)*DM + col] = (bf16_t)(a4[rr] + bv);
        } else if (col < 2*DM){
          const int cc = col - DM;
          const float bv = b1p[cc];
#pragma unroll
          for (int rr = 0; rr < 4; ++rr)
            o1[(size_t)(row0+rr)*DM + cc] = (bf16_t)(a4[rr] + bv);
        } else {
          const int cc = col - 2*DM;
          const float bv = b2p[cc];
          const int hh = cc & 15, dd = cc >> 4;
          unsigned short us[4];
#pragma unroll
          for (int rr = 0; rr < 4; ++rr) us[rr] = bfbits(a4[rr] + bv);
          *(ushort4*)&o2[(size_t)(hh*DHD + dd)*SEQL + row0] =
              make_ushort4(us[0], us[1], us[2], us[3]);
        }
      } else if constexpr (EPI == E_FFN1){
        const float bv = b0p[col];
#pragma unroll
        for (int rr = 0; rr < 4; ++rr){
          const float v = a4[rr] + bv;
          const float z = v * (v*v*0.044715f + 1.0f) * 1.5957691216f;
          const float gg = v / (1.0f + __expf(-z));
          o0[(size_t)(row0+rr)*FFH + col] = (bf16_t)gg;
        }
      }
    }
  }
}

// ---------------------------------------------------------------------------
// Gather Q/K flat [row][16d+h] -> head layout [h][row][d] (pure bit-move).
__global__ __launch_bounds__(256)
void permute_qk(const bf16_t* __restrict__ Qf, const bf16_t* __restrict__ Kf,
                bf16_t* __restrict__ Qhd, bf16_t* __restrict__ Khd)
{
  const int row = blockIdx.x, which = blockIdx.y, tid = threadIdx.x;
  const bf16_t* src = (which ? Kf : Qf) + (size_t)row * DM;
  bf16_t* dst = which ? Khd : Qhd;
  const int hh = tid >> 4, d0 = (tid & 15) * 8;
  unsigned short us[8];
#pragma unroll
  for (int j = 0; j < 8; ++j)
    us[j] = __builtin_bit_cast(unsigned short, src[(d0 + j)*NH + hh]);
  uint4 o;
  o.x = (unsigned)us[0] | ((unsigned)us[1] << 16);
  o.y = (unsigned)us[2] | ((unsigned)us[3] << 16);
  o.z = (unsigned)us[4] | ((unsigned)us[5] << 16);
  o.w = (unsigned)us[6] | ((unsigned)us[7] << 16);
  *(uint4*)&dst[(size_t)hh*(SEQL*DHD) + (size_t)row*DHD + d0] = o;
}

// ---------------------------------------------------------------------------
// Attention (flattened grid; blocks >= attnN run cvt). One block per
// (32 q-rows, head); full softmax over 512 keys.
template<int NCVT>
__global__ __launch_bounds__(256)
void attn_cvt(const bf16_t* __restrict__ Qh, const bf16_t* __restrict__ Kh,
              const bf16_t* __restrict__ Vt, bf16_t* __restrict__ Aout,
              int attnN, CvtA3 cva)
{
  if constexpr (NCVT > 0){
    if ((int)blockIdx.x >= attnN){
      cvt_block8k<NCVT>(cva.s, (int)blockIdx.x - attnN);
      return;
    }
  }
  __shared__ bf16_t Pl[32*512];
  __shared__ float redm[4][32];
  __shared__ float reds[4][32];
  const int tid = threadIdx.x;
  const int lane = tid & 63, w = tid >> 6;
  const int c = lane & 15, g = lane >> 4;
  const int h  = (int)blockIdx.x >> 4;
  const int rb = ((int)blockIdx.x & 15) * 32;
  const bf16_t* Qb = Qh + (size_t)h * (SEQL*DHD);
  const bf16_t* Kb = Kh + (size_t)h * (SEQL*DHD);
  const bf16_t* Vb = Vt + (size_t)h * (SEQL*DHD);

  bf16x8 qf[2][4];
#pragma unroll
  for (int a = 0; a < 2; ++a)
#pragma unroll
    for (int ks = 0; ks < 4; ++ks)
      qf[a][ks] = *(const bf16x8*)(Qb + (size_t)(rb + a*16 + c)*DHD + ks*32 + g*8);

  f32x4 s[2][8] = {};
#pragma unroll
  for (int ks = 0; ks < 4; ++ks)
#pragma unroll
    for (int b = 0; b < 8; ++b){
      const bf16x8 kf = *(const bf16x8*)(Kb + (size_t)(w*128 + b*16 + c)*DHD + ks*32 + g*8);
      s[0][b] = __builtin_amdgcn_mfma_f32_16x16x32_bf16(qf[0][ks], kf, s[0][b], 0,0,0);
      s[1][b] = __builtin_amdgcn_mfma_f32_16x16x32_bf16(qf[1][ks], kf, s[1][b], 0,0,0);
    }
#pragma unroll
  for (int a = 0; a < 2; ++a)
#pragma unroll
    for (int b = 0; b < 8; ++b)
#pragma unroll
      for (int rr = 0; rr < 4; ++rr) s[a][b][rr] *= 0.022097086912079612f;

  float mx[2][4], sm[2][4], inv[2][4];
#pragma unroll
  for (int a = 0; a < 2; ++a)
#pragma unroll
    for (int rr = 0; rr < 4; ++rr){
      float m = s[a][0][rr];
#pragma unroll
      for (int b = 1; b < 8; ++b) m = fmaxf(m, s[a][b][rr]);
#pragma unroll
      for (int off = 1; off < 16; off <<= 1) m = fmaxf(m, __shfl_xor(m, off));
      mx[a][rr] = m;
    }
  if (c == 0)
#pragma unroll
    for (int a = 0; a < 2; ++a)
#pragma unroll
      for (int rr = 0; rr < 4; ++rr) redm[w][a*16 + 4*g + rr] = mx[a][rr];
  __syncthreads();
#pragma unroll
  for (int a = 0; a < 2; ++a)
#pragma unroll
    for (int rr = 0; rr < 4; ++rr){
      const int lr = a*16 + 4*g + rr;
      mx[a][rr] = fmaxf(fmaxf(redm[0][lr], redm[1][lr]), fmaxf(redm[2][lr], redm[3][lr]));
      sm[a][rr] = 0.f;
    }
#pragma unroll
  for (int a = 0; a < 2; ++a)
#pragma unroll
    for (int b = 0; b < 8; ++b)
#pragma unroll
      for (int rr = 0; rr < 4; ++rr){
        const float p = __expf(s[a][b][rr] - mx[a][rr]);
        s[a][b][rr] = p;
        sm[a][rr] += p;
      }
#pragma unroll
  for (int a = 0; a < 2; ++a)
#pragma unroll
    for (int rr = 0; rr < 4; ++rr){
#pragma unroll
      for (int off = 1; off < 16; off <<= 1) sm[a][rr] += __shfl_xor(sm[a][rr], off);
    }
  if (c == 0)
#pragma unroll
    for (int a = 0; a < 2; ++a)
#pragma unroll
      for (int rr = 0; rr < 4; ++rr) reds[w][a*16 + 4*g + rr] = sm[a][rr];
  __syncthreads();
#pragma unroll
  for (int a = 0; a < 2; ++a)
#pragma unroll
    for (int rr = 0; rr < 4; ++rr){
      const int lr = a*16 + 4*g + rr;
      inv[a][rr] = 1.0f / (reds[0][lr] + reds[1][lr] + reds[2][lr] + reds[3][lr]);
    }

#pragma unroll
  for (int a = 0; a < 2; ++a)
#pragma unroll
    for (int b = 0; b < 8; ++b)
#pragma unroll
      for (int rr = 0; rr < 4; ++rr){
        const int lr  = a*16 + 4*g + rr;
        const int key = w*128 + b*16 + c;
        const int slot = (key >> 3) ^ (lr & 7);
        Pl[lr*512 + slot*8 + (key & 7)] = (bf16_t)(s[a][b][rr] * inv[a][rr]);
      }
  __syncthreads();

  f32x4 o[2][2] = {};
  const int dw = w * 32;
#pragma unroll
  for (int kst = 0; kst < 16; ++kst){
    bf16x8 pa2[2];
#pragma unroll
    for (int a = 0; a < 2; ++a){
      const int r = a*16 + c;
      const int slot = (kst*4 + g) ^ (r & 7);
      pa2[a] = *(const bf16x8*)&Pl[r*512 + slot*8];
    }
#pragma unroll
    for (int db = 0; db < 2; ++db){
      const bf16x8 vf = *(const bf16x8*)(Vb + (size_t)(dw + db*16 + c)*SEQL + kst*32 + g*8);
      o[0][db] = __builtin_amdgcn_mfma_f32_16x16x32_bf16(pa2[0], vf, o[0][db], 0,0,0);
      o[1][db] = __builtin_amdgcn_mfma_f32_16x16x32_bf16(pa2[1], vf, o[1][db], 0,0,0);
    }
  }
#pragma unroll
  for (int a = 0; a < 2; ++a)
#pragma unroll
    for (int db = 0; db < 2; ++db)
#pragma unroll
      for (int rr = 0; rr < 4; ++rr){
        const int row  = rb + a*16 + 4*g + rr;
        const int col2 = h*DHD + dw + db*16 + c;
        Aout[(size_t)row*DM + col2] = (bf16_t)o[a][db][rr];
      }
}

// ---------------------------------------------------------------------------
// reduce S split-K partials + bias + positional encoding -> X fp32 + XB bf16
template<int S>
__global__ __launch_bounds__(256)
void reduce_pos(const float* __restrict__ P, const float* __restrict__ bias,
                float* __restrict__ X, bf16_t* __restrict__ XB)
{
  const int row = blockIdx.x, c0 = threadIdx.x * 8;
  const size_t base = (size_t)row * DM + c0;
  float y[8];
#pragma unroll
  for (int j = 0; j < 8; ++j) y[j] = bias[c0 + j];
#pragma unroll
  for (int s = 0; s < S; ++s){
    const float4 v0 = *(const float4*)(P + s*PST + base);
    const float4 v1 = *(const float4*)(P + s*PST + base + 4);
    y[0]+=v0.x; y[1]+=v0.y; y[2]+=v0.z; y[3]+=v0.w;
    y[4]+=v1.x; y[5]+=v1.y; y[6]+=v1.z; y[7]+=v1.w;
  }
#pragma unroll
  for (int j = 0; j < 8; ++j){
    const int col = c0 + j;
    const float fr  = 1e-4f * __expf(-(float)(col >> 1) * (1.0f/1024.0f));
    const float ang = (float)row * fr;
    y[j] += (col & 1) ? __cosf(ang) : __sinf(ang);
  }
  *(float4*)(X + base)     = make_float4(y[0], y[1], y[2], y[3]);
  *(float4*)(X + base + 4) = make_float4(y[4], y[5], y[6], y[7]);
  uint4 ob;
  ob.x = pack2(y[0], y[1]); ob.y = pack2(y[2], y[3]);
  ob.z = pack2(y[4], y[5]); ob.w = pack2(y[6], y[7]);
  *(uint4*)&XB[base] = ob;
}

// ---------------------------------------------------------------------------
// reduce S split-K partials + bias + residual, then row-LayerNorm(2048).
template<int S, int WB>
__global__ __launch_bounds__(256)
void reduce_ln(const float* __restrict__ P, const float* __restrict__ bias,
               const float* __restrict__ resid, const float* __restrict__ gam,
               const float* __restrict__ bet, float* __restrict__ outF,
               bf16_t* __restrict__ outB)
{
  const int row = blockIdx.x, tid = threadIdx.x, c0 = tid * 8;
  const size_t base = (size_t)row * DM + c0;
  float y[8];
  {
    const float4 r0 = *(const float4*)(resid + base);
    const float4 r1 = *(const float4*)(resid + base + 4);
    y[0]=r0.x; y[1]=r0.y; y[2]=r0.z; y[3]=r0.w;
    y[4]=r1.x; y[5]=r1.y; y[6]=r1.z; y[7]=r1.w;
  }
#pragma unroll
  for (int j = 0; j < 8; ++j) y[j] += bias[c0 + j];
#pragma unroll
  for (int s = 0; s < S; ++s){
    const float4 v0 = *(const float4*)(P + s*PST + base);
    const float4 v1 = *(const float4*)(P + s*PST + base + 4);
    y[0]+=v0.x; y[1]+=v0.y; y[2]+=v0.z; y[3]+=v0.w;
    y[4]+=v1.x; y[5]+=v1.y; y[6]+=v1.z; y[7]+=v1.w;
  }
  float sm = 0.f, qs = 0.f;
#pragma unroll
  for (int j = 0; j < 8; ++j){ sm += y[j]; qs += y[j]*y[j]; }
#pragma unroll
  for (int off = 32; off >= 1; off >>= 1){
    sm += __shfl_xor(sm, off); qs += __shfl_xor(qs, off);
  }
  __shared__ float rs[4], rq[4];
  const int w = tid >> 6;
  if ((tid & 63) == 0){ rs[w] = sm; rq[w] = qs; }
  __syncthreads();
  sm = rs[0]+rs[1]+rs[2]+rs[3];
  qs = rq[0]+rq[1]+rq[2]+rq[3];
  const float mu   = sm * (1.0f/2048.0f);
  const float var  = qs * (1.0f/2048.0f) - mu*mu;
  const float rstd = rsqrtf(var + 1e-5f);
  const float4 g0 = *(const float4*)(gam + c0);
  const float4 g1 = *(const float4*)(gam + c0 + 4);
  const float4 b0 = *(const float4*)(bet + c0);
  const float4 b1 = *(const float4*)(bet + c0 + 4);
  float o[8];
  o[0] = (y[0]-mu)*rstd*g0.x + b0.x;  o[1] = (y[1]-mu)*rstd*g0.y + b0.y;
  o[2] = (y[2]-mu)*rstd*g0.z + b0.z;  o[3] = (y[3]-mu)*rstd*g0.w + b0.w;
  o[4] = (y[4]-mu)*rstd*g1.x + b1.x;  o[5] = (y[5]-mu)*rstd*g1.y + b1.y;
  o[6] = (y[6]-mu)*rstd*g1.z + b1.z;  o[7] = (y[7]-mu)*rstd*g1.w + b1.w;
  *(float4*)(outF + base)     = make_float4(o[0], o[1], o[2], o[3]);
  *(float4*)(outF + base + 4) = make_float4(o[4], o[5], o[6], o[7]);
  if constexpr (WB){
    uint4 ob;
    ob.x = pack2(o[0], o[1]); ob.y = pack2(o[2], o[3]);
    ob.z = pack2(o[4], o[5]); ob.w = pack2(o[6], o[7]);
    *(uint4*)&outB[base] = ob;
  }
}

// ---------------------------------------------------------------------------
extern "C" void kernel_launch(void* const* d_in, const int* in_sizes, int n_in,
                              void* d_out, int out_size, void* d_ws, size_t ws_size,
                              hipStream_t stream)
{
  const float* seq   = (const float*)d_in[0];
  const float* emb_W = (const float*)d_in[1];
  const float* emb_b = (const float*)d_in[2];
  const float* Wq = (const float*)d_in[3];  const float* bq = (const float*)d_in[4];
  const float* Wk = (const float*)d_in[5];  const float* bk = (const float*)d_in[6];
  const float* Wv = (const float*)d_in[7];  const float* bv = (const float*)d_in[8];
  const float* Wo = (const float*)d_in[9];  const float* bo = (const float*)d_in[10];
  const float* ln_g = (const float*)d_in[11]; const float* ln_b = (const float*)d_in[12];
  const float* W1 = (const float*)d_in[13]; const float* b1 = (const float*)d_in[14];
  const float* W2 = (const float*)d_in[15]; const float* b2 = (const float*)d_in[16];

  char* ws = (char*)d_ws;
  size_t off = 0;
  auto take = [&](size_t bytes) -> void* {
    void* p = ws + off;
    off += (bytes + 255) & ~(size_t)255;
    return p;
  };
  bf16_t* seqB = (bf16_t*)take((size_t)SEQL*DM*2);
  bf16_t* WeB  = (bf16_t*)take((size_t)DM*DM*2);
  bf16_t* WqB  = (bf16_t*)take((size_t)DM*DM*2);
  bf16_t* WkB  = (bf16_t*)take((size_t)DM*DM*2);
  bf16_t* WvB  = (bf16_t*)take((size_t)DM*DM*2);
  bf16_t* WoB  = (bf16_t*)take((size_t)DM*DM*2);
  bf16_t* W1B  = (bf16_t*)take((size_t)DM*FFH*2);
  bf16_t* W2B  = (bf16_t*)take((size_t)FFH*DM*2);
  float*  X    = (float*) take((size_t)SEQL*DM*4);
  bf16_t* XB   = (bf16_t*)take((size_t)SEQL*DM*2);
  bf16_t* Qf   = (bf16_t*)take((size_t)SEQL*DM*2);
  bf16_t* Kf   = (bf16_t*)take((size_t)SEQL*DM*2);
  bf16_t* Qhd  = (bf16_t*)take((size_t)SEQL*DM*2);
  bf16_t* Khd  = (bf16_t*)take((size_t)SEQL*DM*2);
  bf16_t* Vt   = (bf16_t*)take((size_t)SEQL*DM*2);
  bf16_t* Afl  = (bf16_t*)take((size_t)SEQL*DM*2);
  float*  Pp   = (float*) take((size_t)8*SEQL*DM*4);  // split-K partials (32 MB)
  float*  Xa   = (float*) take((size_t)SEQL*DM*4);
  bf16_t* XaB  = (bf16_t*)take((size_t)SEQL*DM*2);
  bf16_t* Hb   = (bf16_t*)take((size_t)SEQL*FFH*2);
  (void)ws_size; (void)in_sizes; (void)n_in; (void)out_size;

  CvtA3 cz = {};  // dummy

  // pass 0: seq (128 blocks) + emb_W (512 blocks)
  CvtA3 c0 = {};
  c0.s[0] = { seq,   seqB, 0 };
  c0.s[1] = { emb_W, WeB,  128 };
  cvt8k<2><<<dim3(640), 256, 0, stream>>>(c0);

  // embedding GEMM (split-K x4, 512 gemm blocks) + cvt Wq/Wk/Wv (1536 blocks)
  CvtA3 cq = {};
  cq.s[0] = { Wq, WqB, 0 };
  cq.s[1] = { Wk, WkB, 512 };
  cq.s[2] = { Wv, WvB, 1024 };
  gemmT<E_PART,0,64,3><<<dim3(2048), 256, 0, stream>>>(seqB, WeB, nullptr, nullptr,
      nullptr, nullptr, nullptr, Pp, nullptr, nullptr, nullptr, 16, DM, DM, 512, 512, cq);
  reduce_pos<4><<<SEQL, 256, 0, stream>>>(Pp, emb_b, X, XB);

  // fused QKV (BM=32, 768 gemm blocks) + cvt W1 (2048 blocks)
  CvtA3 c1 = {};
  c1.s[0] = { W1, W1B, 0 };
  gemmT<E_QKV,0,32,1><<<dim3(2816), 256, 0, stream>>>(XB, WqB, WkB, WvB,
      bq, bk, bv, nullptr, Qf, Kf, Vt, 48, DM, DM, DM, 768, c1);
  permute_qk<<<dim3(SEQL,2), 256, 0, stream>>>(Qf, Kf, Qhd, Khd);

  // attention (256 blocks) + cvt Wo (512) + cvt W2 (2048)
  CvtA3 c2 = {};
  c2.s[0] = { Wo, WoB, 0 };
  c2.s[1] = { W2, W2B, 512 };
  attn_cvt<2><<<dim3(2816), 256, 0, stream>>>(Qhd, Khd, Vt, Afl, 256, c2);

  // output projection (split-K x4, k-permuted Wo rows) + residual + LN1
  gemmT<E_PART,1,64,0><<<dim3(512), 256, 0, stream>>>(Afl, WoB, nullptr, nullptr,
      nullptr, nullptr, nullptr, Pp, nullptr, nullptr, nullptr, 16, DM, DM, 512, 512, cz);
  reduce_ln<4,1><<<SEQL, 256, 0, stream>>>(Pp, bo, X, ln_g, ln_b, Xa, XaB);

  // FFN1 (BM=32, 1024 blocks)
  gemmT<E_FFN1,0,32,0><<<dim3(1024), 256, 0, stream>>>(XaB, W1B, nullptr, nullptr,
      b1, nullptr, nullptr, nullptr, Hb, nullptr, nullptr, 64, FFH, DM, DM, 1024, cz);

  // FFN2 (split-K x8, Kc=1024, 1024 blocks) + residual + LN2 -> out
  gemmT<E_PART,0,64,0><<<dim3(1024), 256, 0, stream>>>(Hb, W2B, nullptr, nullptr,
      nullptr, nullptr, nullptr, Pp, nullptr, nullptr, nullptr, 16, DM, FFH, 1024, 1024, cz);
  reduce_ln<8,0><<<SEQL, 256, 0, stream>>>(Pp, b2, Xa, ln_g, ln_b, (float*)d_out, nullptr);
}

// Round 10
// 222.555 us; speedup vs baseline: 1.2651x; 1.0045x over previous
//
#include <hip/hip_runtime.h>
#include <hip/hip_bf16.h>

// ---------------------------------------------------------------------------
// TransformerEncoder forward on MI355X (gfx950). Round 9:
//   - K-loop: counted-vmcnt 2-buffer pipeline. Per iter:
//       COMPUTE(buf); barrier; STAGE(buf, kt+2); vmcnt(NL); barrier
//     NL = gll16s per thread per STAGE (5 for BM=32, 6 for BM=64) -> the wait
//     retires tile kt+1's loads while kt+2's stay in flight across the
//     barrier. Halves the per-iteration latency stall vs round 8's vmcnt(0).
//   - cvt riders rebalanced: emb kernel converts Wq/Wk/Wv/Wo, QKV converts
//     W1, attention converts W2 (~96 MB each).
// ---------------------------------------------------------------------------

typedef __bf16 bf16_t;
typedef __bf16 bf16x4 __attribute__((ext_vector_type(4)));
typedef __bf16 bf16x8 __attribute__((ext_vector_type(8)));
typedef float  f32x4  __attribute__((ext_vector_type(4)));

#define SEQL 512
#define DM   2048
#define FFH  8192
#define NH   16
#define DHD  128
#define PST  ((size_t)SEQL*DM)   // partial-slice stride

__device__ __forceinline__ unsigned short bfbits(float f){
  bf16_t h = (bf16_t)f;
  return __builtin_bit_cast(unsigned short, h);
}
__device__ __forceinline__ unsigned int pack2(float a, float b){
  return (unsigned int)bfbits(a) | ((unsigned int)bfbits(b) << 16);
}

__device__ __forceinline__ void gll16(const bf16_t* g, bf16_t* l){
  __builtin_amdgcn_global_load_lds(
      (const __attribute__((address_space(1))) void*)g,
      (__attribute__((address_space(3))) void*)l, 16, 0, 0);
}
__device__ __forceinline__ unsigned lds_off(const void* p){
  return (unsigned)(uintptr_t)(const __attribute__((address_space(3))) void*)p;
}

// ---------------------------------------------------------------------------
// Streaming fp32 -> bf16 convert. One block = 8192 consecutive floats
// (4 chunks of 2048; 8 loads issued before the 4 stores for MLP).
struct CvtSeg { const float* src; bf16_t* dst; int base; };  // base in 8192-float blocks
struct CvtA4  { CvtSeg s[4]; };

template<int NS>
__device__ __forceinline__ void cvt_block8k(const CvtSeg* segs, int b){
  int i = 0;
#pragma unroll
  for (int j = 1; j < NS; ++j) if (b >= segs[j].base) i = j;
  const float* src = segs[i].src;
  bf16_t* dst = segs[i].dst;
  const size_t off0 = (size_t)(b - segs[i].base) * 8192 + threadIdx.x * 8;
  f32x4 v[8];
#pragma unroll
  for (int it = 0; it < 4; ++it){
    v[2*it]   = *(const f32x4*)(src + off0 + it*2048);
    v[2*it+1] = *(const f32x4*)(src + off0 + it*2048 + 4);
  }
#pragma unroll
  for (int it = 0; it < 4; ++it){
    uint4 o;
    o.x = pack2(v[2*it][0],   v[2*it][1]);
    o.y = pack2(v[2*it][2],   v[2*it][3]);
    o.z = pack2(v[2*it+1][0], v[2*it+1][1]);
    o.w = pack2(v[2*it+1][2], v[2*it+1][3]);
    *(uint4*)(dst + off0 + it*2048) = o;
  }
}

template<int NS>
__global__ __launch_bounds__(256)
void cvt8k(CvtA4 a){ cvt_block8k<NS>(a.s, blockIdx.x); }

// ---------------------------------------------------------------------------
// GEMM: C[512][N] = A[512][K](bf16) @ WB[K][N](bf16, HW-transposed via tr_b16).
// Blocks >= gemmN run the cvt rider instead.
constexpr int E_PART = 0;  // fp32 partial (no bias) -> outF + zt*PST
constexpr int E_QKV  = 1;  // [0,2k)->Qf flat, [2k,4k)->Kf flat, rest->Vt[h][d][key]
constexpr int E_FFN1 = 2;  // bias + gelu -> bf16 [512][FFH]

template<int EPI, int PERM, int BM, int NCVT>
__global__ __launch_bounds__(256, (BM == 64) ? 3 : 4)
void gemmT(const bf16_t* __restrict__ A,
           const bf16_t* __restrict__ B0, const bf16_t* __restrict__ B1,
           const bf16_t* __restrict__ B2,
           const float* __restrict__ b0p, const float* __restrict__ b1p,
           const float* __restrict__ b2p,
           float* __restrict__ outF, bf16_t* __restrict__ o0,
           bf16_t* __restrict__ o1, bf16_t* __restrict__ o2,
           int nn, int Nw, int K, int Kc, int gemmN, CvtA4 cva)
{
  if constexpr (NCVT > 0){
    if ((int)blockIdx.x >= gemmN){
      cvt_block8k<NCVT>(cva.s, (int)blockIdx.x - gemmN);
      return;
    }
  }
  constexpr int NF    = (BM == 64) ? 4 : 2;
  constexpr int APASS = BM / 32;
  constexpr int MTM   = (BM == 64) ? 7 : 15;
  constexpr int MTS   = (BM == 64) ? 3 : 4;
  __shared__ bf16_t sA[2][BM*64];
  __shared__ bf16_t sB[2][128*64];
  const int tid  = threadIdx.x;
  const int lane = tid & 63, w = tid >> 6;
  const int wr4 = (BM == 64) ? (w >> 1) : 0;
  const int wc  = (BM == 64) ? (w & 1)  : w;
  const int c = lane & 15, g = lane >> 4;

  // grid decode (XCD swizzle, m-fastest) over the gemm sub-grid only
  const int cpx = gemmN >> 3;
  const int sblk = ((int)blockIdx.x & 7) * cpx + ((int)blockIdx.x >> 3);
  const int mt = sblk & MTM, q2 = sblk >> MTS;
  const int nt = q2 % nn, zt = q2 / nn;
  const int m0 = mt * BM, k0 = zt * Kc;

  // weight select (QKV: three separate [2048][2048] sources)
  const bf16_t* Bsel = B0; int nb0 = nt * 128;
  if constexpr (EPI == E_QKV){
    if (nt >= 32){ Bsel = B2; nb0 = (nt - 32) * 128; }
    else if (nt >= 16){ Bsel = B1; nb0 = (nt - 16) * 128; }
  }

  // A staging
  const int arow = tid >> 3;
  const int acol = (((tid & 7) ^ ((tid >> 3) & 7)) << 3);
  const bf16_t* Aps[APASS];
#pragma unroll
  for (int pa = 0; pa < APASS; ++pa)
    Aps[pa] = A + (size_t)(m0 + pa*32 + arow) * K + k0 + acol;

  // B staging: per-lane pre-swizzled source
  const int klB  = (lane >> 3) * 4 + ((lane >> 1) & 3);
  const int colB = nb0 + w*16 + (lane & 1)*8;
  const bf16_t* Bph[2];
  if constexpr (!PERM){
#pragma unroll
    for (int h = 0; h < 2; ++h)
      Bph[h] = Bsel + (size_t)(k0 + h*32 + klB) * Nw + colB;
  }

  const unsigned sBbase[2] = { lds_off(&sB[0][0]), lds_off(&sB[1][0]) };
  const unsigned trLane = (unsigned)(g*256 + c*8);

  f32x4 acc[2][NF] = {};
  const int nk = Kc >> 6;

#define STAGE(bf, kt) {                                                     \
    _Pragma("unroll")                                                       \
    for (int pa = 0; pa < APASS; ++pa)                                      \
      gll16(Aps[pa] + (size_t)(kt)*64, &sA[bf][(pa*256 + tid)*8]);          \
    _Pragma("unroll")                                                       \
    for (int h = 0; h < 2; ++h)                                             \
      _Pragma("unroll")                                                     \
      for (int p = 0; p < 2; ++p){                                          \
        const bf16_t* src;                                                  \
        if constexpr (PERM){                                                \
          const int kr = k0 + (kt)*64 + h*32 + klB;                         \
          const int krow = ((kr & 127) << 4) + (kr >> 7);                   \
          src = Bsel + (size_t)krow * Nw + colB + p*64;                     \
        } else {                                                            \
          src = Bph[h] + (size_t)(kt)*64*Nw + p*64;                         \
        }                                                                   \
        gll16(src, &sB[bf][h*4096 + (p*256 + tid)*8]);                      \
      } }

#define COMPUTE(PB) {                                                       \
    bf16x8 af[2][2]; bf16x8 bq[NF][2];                                      \
    _Pragma("unroll")                                                       \
    for (int m = 0; m < 2; ++m)                                             \
      _Pragma("unroll")                                                     \
      for (int ks = 0; ks < 2; ++ks){                                       \
        const int r = wr4*32 + m*16 + c;                                    \
        af[m][ks] = *(const bf16x8*)&sA[PB][r*64 + (((ks*4+g) ^ (r&7))<<3)];\
      }                                                                     \
    { const unsigned base = sBbase[PB] + (unsigned)(wc*NF*1024) + trLane;   \
      _Pragma("unroll")                                                     \
      for (int n = 0; n < NF; ++n)                                          \
        _Pragma("unroll")                                                   \
        for (int ks = 0; ks < 2; ++ks){                                     \
          bf16x4 r0, r1;                                                    \
          const unsigned a2 = base + (unsigned)(n*1024 + ks*8192);          \
          asm volatile("ds_read_b64_tr_b16 %0, %1" : "=v"(r0) : "v"(a2));   \
          asm volatile("ds_read_b64_tr_b16 %0, %1 offset:128" : "=v"(r1) : "v"(a2)); \
          bq[n][ks] = __builtin_shufflevector(r0, r1, 0,1,2,3,4,5,6,7);     \
        } }                                                                 \
    asm volatile("s_waitcnt lgkmcnt(0)" ::: "memory");                      \
    __builtin_amdgcn_sched_barrier(0);                                      \
    _Pragma("unroll")                                                       \
    for (int m = 0; m < 2; ++m)                                             \
      _Pragma("unroll")                                                     \
      for (int n = 0; n < NF; ++n)                                          \
        _Pragma("unroll")                                                   \
        for (int ks = 0; ks < 2; ++ks)                                      \
          acc[m][n] = __builtin_amdgcn_mfma_f32_16x16x32_bf16(af[m][ks], bq[n][ks], acc[m][n], 0,0,0); }

#define WAIT_NL() {                                                         \
    if constexpr (BM == 64) asm volatile("s_waitcnt vmcnt(6)" ::: "memory");\
    else                    asm volatile("s_waitcnt vmcnt(5)" ::: "memory");}

  // prologue: two tiles in flight; wait only tile0 (tile1's NL stay in flight)
  STAGE(0, 0);
  STAGE(1, 1);
  WAIT_NL();
  __builtin_amdgcn_s_barrier();
  __builtin_amdgcn_sched_barrier(0);

  int buf = 0;
  for (int kt = 0; kt < nk; ++kt){
    COMPUTE(buf);
    __builtin_amdgcn_s_barrier();          // all waves done reading buf
    __builtin_amdgcn_sched_barrier(0);
    if (kt + 1 < nk){
      if (kt + 2 < nk){
        STAGE(buf, kt + 2);                // refill freed buffer
        WAIT_NL();                         // tile kt+1 landed; kt+2 in flight
      } else {
        asm volatile("s_waitcnt vmcnt(0)" ::: "memory");
      }
      __builtin_amdgcn_s_barrier();
      __builtin_amdgcn_sched_barrier(0);
    }
    buf ^= 1;
  }
#undef STAGE
#undef COMPUTE
#undef WAIT_NL

  // epilogue
#pragma unroll
  for (int n = 0; n < NF; ++n){
    const int col = nt*128 + wc*(NF*16) + n*16 + c;
#pragma unroll
    for (int m = 0; m < 2; ++m){
      const int row0 = m0 + wr4*32 + m*16 + 4*g;
      const f32x4 a4 = acc[m][n];
      if constexpr (EPI == E_PART){
        float* dst = outF + (size_t)zt * PST;
#pragma unroll
        for (int rr = 0; rr < 4; ++rr)
          dst[(size_t)(row0+rr)*DM + col] = a4[rr];
      } else if constexpr (EPI == E_QKV){
        if (col < DM){
          const float bv = b0p[col];
#pragma unroll
          for (int rr = 0; rr < 4; ++rr)
            o0[(size_t)(row0+rr)*DM + col] = (bf16_t)(a4[rr] + bv);
        } else if (col < 2*DM){
          const int cc = col - DM;
          const float bv = b1p[cc];
#pragma unroll
          for (int rr = 0; rr < 4; ++rr)
            o1[(size_t)(row0+rr)*DM + cc] = (bf16_t)(a4[rr] + bv);
        } else {
          const int cc = col - 2*DM;
          const float bv = b2p[cc];
          const int hh = cc & 15, dd = cc >> 4;
          unsigned short us[4];
#pragma unroll
          for (int rr = 0; rr < 4; ++rr) us[rr] = bfbits(a4[rr] + bv);
          *(ushort4*)&o2[(size_t)(hh*DHD + dd)*SEQL + row0] =
              make_ushort4(us[0], us[1], us[2], us[3]);
        }
      } else if constexpr (EPI == E_FFN1){
        const float bv = b0p[col];
#pragma unroll
        for (int rr = 0; rr < 4; ++rr){
          const float v = a4[rr] + bv;
          const float z = v * (v*v*0.044715f + 1.0f) * 1.5957691216f;
          const float gg = v / (1.0f + __expf(-z));
          o0[(size_t)(row0+rr)*FFH + col] = (bf16_t)gg;
        }
      }
    }
  }
}

// ---------------------------------------------------------------------------
// Gather Q/K flat [row][16d+h] -> head layout [h][row][d] (pure bit-move).
__global__ __launch_bounds__(256)
void permute_qk(const bf16_t* __restrict__ Qf, const bf16_t* __restrict__ Kf,
                bf16_t* __restrict__ Qhd, bf16_t* __restrict__ Khd)
{
  const int row = blockIdx.x, which = blockIdx.y, tid = threadIdx.x;
  const bf16_t* src = (which ? Kf : Qf) + (size_t)row * DM;
  bf16_t* dst = which ? Khd : Qhd;
  const int hh = tid >> 4, d0 = (tid & 15) * 8;
  unsigned short us[8];
#pragma unroll
  for (int j = 0; j < 8; ++j)
    us[j] = __builtin_bit_cast(unsigned short, src[(d0 + j)*NH + hh]);
  uint4 o;
  o.x = (unsigned)us[0] | ((unsigned)us[1] << 16);
  o.y = (unsigned)us[2] | ((unsigned)us[3] << 16);
  o.z = (unsigned)us[4] | ((unsigned)us[5] << 16);
  o.w = (unsigned)us[6] | ((unsigned)us[7] << 16);
  *(uint4*)&dst[(size_t)hh*(SEQL*DHD) + (size_t)row*DHD + d0] = o;
}

// ---------------------------------------------------------------------------
// Attention (flattened grid; blocks >= attnN run cvt). One block per
// (32 q-rows, head); full softmax over 512 keys.
template<int NCVT>
__global__ __launch_bounds__(256)
void attn_cvt(const bf16_t* __restrict__ Qh, const bf16_t* __restrict__ Kh,
              const bf16_t* __restrict__ Vt, bf16_t* __restrict__ Aout,
              int attnN, CvtA4 cva)
{
  if constexpr (NCVT > 0){
    if ((int)blockIdx.x >= attnN){
      cvt_block8k<NCVT>(cva.s, (int)blockIdx.x - attnN);
      return;
    }
  }
  __shared__ bf16_t Pl[32*512];
  __shared__ float redm[4][32];
  __shared__ float reds[4][32];
  const int tid = threadIdx.x;
  const int lane = tid & 63, w = tid >> 6;
  const int c = lane & 15, g = lane >> 4;
  const int h  = (int)blockIdx.x >> 4;
  const int rb = ((int)blockIdx.x & 15) * 32;
  const bf16_t* Qb = Qh + (size_t)h * (SEQL*DHD);
  const bf16_t* Kb = Kh + (size_t)h * (SEQL*DHD);
  const bf16_t* Vb = Vt + (size_t)h * (SEQL*DHD);

  bf16x8 qf[2][4];
#pragma unroll
  for (int a = 0; a < 2; ++a)
#pragma unroll
    for (int ks = 0; ks < 4; ++ks)
      qf[a][ks] = *(const bf16x8*)(Qb + (size_t)(rb + a*16 + c)*DHD + ks*32 + g*8);

  f32x4 s[2][8] = {};
#pragma unroll
  for (int ks = 0; ks < 4; ++ks)
#pragma unroll
    for (int b = 0; b < 8; ++b){
      const bf16x8 kf = *(const bf16x8*)(Kb + (size_t)(w*128 + b*16 + c)*DHD + ks*32 + g*8);
      s[0][b] = __builtin_amdgcn_mfma_f32_16x16x32_bf16(qf[0][ks], kf, s[0][b], 0,0,0);
      s[1][b] = __builtin_amdgcn_mfma_f32_16x16x32_bf16(qf[1][ks], kf, s[1][b], 0,0,0);
    }
#pragma unroll
  for (int a = 0; a < 2; ++a)
#pragma unroll
    for (int b = 0; b < 8; ++b)
#pragma unroll
      for (int rr = 0; rr < 4; ++rr) s[a][b][rr] *= 0.022097086912079612f;

  float mx[2][4], sm[2][4], inv[2][4];
#pragma unroll
  for (int a = 0; a < 2; ++a)
#pragma unroll
    for (int rr = 0; rr < 4; ++rr){
      float m = s[a][0][rr];
#pragma unroll
      for (int b = 1; b < 8; ++b) m = fmaxf(m, s[a][b][rr]);
#pragma unroll
      for (int off = 1; off < 16; off <<= 1) m = fmaxf(m, __shfl_xor(m, off));
      mx[a][rr] = m;
    }
  if (c == 0)
#pragma unroll
    for (int a = 0; a < 2; ++a)
#pragma unroll
      for (int rr = 0; rr < 4; ++rr) redm[w][a*16 + 4*g + rr] = mx[a][rr];
  __syncthreads();
#pragma unroll
  for (int a = 0; a < 2; ++a)
#pragma unroll
    for (int rr = 0; rr < 4; ++rr){
      const int lr = a*16 + 4*g + rr;
      mx[a][rr] = fmaxf(fmaxf(redm[0][lr], redm[1][lr]), fmaxf(redm[2][lr], redm[3][lr]));
      sm[a][rr] = 0.f;
    }
#pragma unroll
  for (int a = 0; a < 2; ++a)
#pragma unroll
    for (int b = 0; b < 8; ++b)
#pragma unroll
      for (int rr = 0; rr < 4; ++rr){
        const float p = __expf(s[a][b][rr] - mx[a][rr]);
        s[a][b][rr] = p;
        sm[a][rr] += p;
      }
#pragma unroll
  for (int a = 0; a < 2; ++a)
#pragma unroll
    for (int rr = 0; rr < 4; ++rr){
#pragma unroll
      for (int off = 1; off < 16; off <<= 1) sm[a][rr] += __shfl_xor(sm[a][rr], off);
    }
  if (c == 0)
#pragma unroll
    for (int a = 0; a < 2; ++a)
#pragma unroll
      for (int rr = 0; rr < 4; ++rr) reds[w][a*16 + 4*g + rr] = sm[a][rr];
  __syncthreads();
#pragma unroll
  for (int a = 0; a < 2; ++a)
#pragma unroll
    for (int rr = 0; rr < 4; ++rr){
      const int lr = a*16 + 4*g + rr;
      inv[a][rr] = 1.0f / (reds[0][lr] + reds[1][lr] + reds[2][lr] + reds[3][lr]);
    }

#pragma unroll
  for (int a = 0; a < 2; ++a)
#pragma unroll
    for (int b = 0; b < 8; ++b)
#pragma unroll
      for (int rr = 0; rr < 4; ++rr){
        const int lr  = a*16 + 4*g + rr;
        const int key = w*128 + b*16 + c;
        const int slot = (key >> 3) ^ (lr & 7);
        Pl[lr*512 + slot*8 + (key & 7)] = (bf16_t)(s[a][b][rr] * inv[a][rr]);
      }
  __syncthreads();

  f32x4 o[2][2] = {};
  const int dw = w * 32;
#pragma unroll
  for (int kst = 0; kst < 16; ++kst){
    bf16x8 pa2[2];
#pragma unroll
    for (int a = 0; a < 2; ++a){
      const int r = a*16 + c;
      const int slot = (kst*4 + g) ^ (r & 7);
      pa2[a] = *(const bf16x8*)&Pl[r*512 + slot*8];
    }
#pragma unroll
    for (int db = 0; db < 2; ++db){
      const bf16x8 vf = *(const bf16x8*)(Vb + (size_t)(dw + db*16 + c)*SEQL + kst*32 + g*8);
      o[0][db] = __builtin_amdgcn_mfma_f32_16x16x32_bf16(pa2[0], vf, o[0][db], 0,0,0);
      o[1][db] = __builtin_amdgcn_mfma_f32_16x16x32_bf16(pa2[1], vf, o[1][db], 0,0,0);
    }
  }
#pragma unroll
  for (int a = 0; a < 2; ++a)
#pragma unroll
    for (int db = 0; db < 2; ++db)
#pragma unroll
      for (int rr = 0; rr < 4; ++rr){
        const int row  = rb + a*16 + 4*g + rr;
        const int col2 = h*DHD + dw + db*16 + c;
        Aout[(size_t)row*DM + col2] = (bf16_t)o[a][db][rr];
      }
}

// ---------------------------------------------------------------------------
// reduce S split-K partials + bias + positional encoding -> X fp32 + XB bf16
template<int S>
__global__ __launch_bounds__(256)
void reduce_pos(const float* __restrict__ P, const float* __restrict__ bias,
                float* __restrict__ X, bf16_t* __restrict__ XB)
{
  const int row = blockIdx.x, c0 = threadIdx.x * 8;
  const size_t base = (size_t)row * DM + c0;
  float y[8];
#pragma unroll
  for (int j = 0; j < 8; ++j) y[j] = bias[c0 + j];
#pragma unroll
  for (int s = 0; s < S; ++s){
    const float4 v0 = *(const float4*)(P + s*PST + base);
    const float4 v1 = *(const float4*)(P + s*PST + base + 4);
    y[0]+=v0.x; y[1]+=v0.y; y[2]+=v0.z; y[3]+=v0.w;
    y[4]+=v1.x; y[5]+=v1.y; y[6]+=v1.z; y[7]+=v1.w;
  }
#pragma unroll
  for (int j = 0; j < 8; ++j){
    const int col = c0 + j;
    const float fr  = 1e-4f * __expf(-(float)(col >> 1) * (1.0f/1024.0f));
    const float ang = (float)row * fr;
    y[j] += (col & 1) ? __cosf(ang) : __sinf(ang);
  }
  *(float4*)(X + base)     = make_float4(y[0], y[1], y[2], y[3]);
  *(float4*)(X + base + 4) = make_float4(y[4], y[5], y[6], y[7]);
  uint4 ob;
  ob.x = pack2(y[0], y[1]); ob.y = pack2(y[2], y[3]);
  ob.z = pack2(y[4], y[5]); ob.w = pack2(y[6], y[7]);
  *(uint4*)&XB[base] = ob;
}

// ---------------------------------------------------------------------------
// reduce S split-K partials + bias + residual, then row-LayerNorm(2048).
template<int S, int WB>
__global__ __launch_bounds__(256)
void reduce_ln(const float* __restrict__ P, const float* __restrict__ bias,
               const float* __restrict__ resid, const float* __restrict__ gam,
               const float* __restrict__ bet, float* __restrict__ outF,
               bf16_t* __restrict__ outB)
{
  const int row = blockIdx.x, tid = threadIdx.x, c0 = tid * 8;
  const size_t base = (size_t)row * DM + c0;
  float y[8];
  {
    const float4 r0 = *(const float4*)(resid + base);
    const float4 r1 = *(const float4*)(resid + base + 4);
    y[0]=r0.x; y[1]=r0.y; y[2]=r0.z; y[3]=r0.w;
    y[4]=r1.x; y[5]=r1.y; y[6]=r1.z; y[7]=r1.w;
  }
#pragma unroll
  for (int j = 0; j < 8; ++j) y[j] += bias[c0 + j];
#pragma unroll
  for (int s = 0; s < S; ++s){
    const float4 v0 = *(const float4*)(P + s*PST + base);
    const float4 v1 = *(const float4*)(P + s*PST + base + 4);
    y[0]+=v0.x; y[1]+=v0.y; y[2]+=v0.z; y[3]+=v0.w;
    y[4]+=v1.x; y[5]+=v1.y; y[6]+=v1.z; y[7]+=v1.w;
  }
  float sm = 0.f, qs = 0.f;
#pragma unroll
  for (int j = 0; j < 8; ++j){ sm += y[j]; qs += y[j]*y[j]; }
#pragma unroll
  for (int off = 32; off >= 1; off >>= 1){
    sm += __shfl_xor(sm, off); qs += __shfl_xor(qs, off);
  }
  __shared__ float rs[4], rq[4];
  const int w = tid >> 6;
  if ((tid & 63) == 0){ rs[w] = sm; rq[w] = qs; }
  __syncthreads();
  sm = rs[0]+rs[1]+rs[2]+rs[3];
  qs = rq[0]+rq[1]+rq[2]+rq[3];
  const float mu   = sm * (1.0f/2048.0f);
  const float var  = qs * (1.0f/2048.0f) - mu*mu;
  const float rstd = rsqrtf(var + 1e-5f);
  const float4 g0 = *(const float4*)(gam + c0);
  const float4 g1 = *(const float4*)(gam + c0 + 4);
  const float4 b0 = *(const float4*)(bet + c0);
  const float4 b1 = *(const float4*)(bet + c0 + 4);
  float o[8];
  o[0] = (y[0]-mu)*rstd*g0.x + b0.x;  o[1] = (y[1]-mu)*rstd*g0.y + b0.y;
  o[2] = (y[2]-mu)*rstd*g0.z + b0.z;  o[3] = (y[3]-mu)*rstd*g0.w + b0.w;
  o[4] = (y[4]-mu)*rstd*g1.x + b1.x;  o[5] = (y[5]-mu)*rstd*g1.y + b1.y;
  o[6] = (y[6]-mu)*rstd*g1.z + b1.z;  o[7] = (y[7]-mu)*rstd*g1.w + b1.w;
  *(float4*)(outF + base)     = make_float4(o[0], o[1], o[2], o[3]);
  *(float4*)(outF + base + 4) = make_float4(o[4], o[5], o[6], o[7]);
  if constexpr (WB){
    uint4 ob;
    ob.x = pack2(o[0], o[1]); ob.y = pack2(o[2], o[3]);
    ob.z = pack2(o[4], o[5]); ob.w = pack2(o[6], o[7]);
    *(uint4*)&outB[base] = ob;
  }
}

// ---------------------------------------------------------------------------
extern "C" void kernel_launch(void* const* d_in, const int* in_sizes, int n_in,
                              void* d_out, int out_size, void* d_ws, size_t ws_size,
                              hipStream_t stream)
{
  const float* seq   = (const float*)d_in[0];
  const float* emb_W = (const float*)d_in[1];
  const float* emb_b = (const float*)d_in[2];
  const float* Wq = (const float*)d_in[3];  const float* bq = (const float*)d_in[4];
  const float* Wk = (const float*)d_in[5];  const float* bk = (const float*)d_in[6];
  const float* Wv = (const float*)d_in[7];  const float* bv = (const float*)d_in[8];
  const float* Wo = (const float*)d_in[9];  const float* bo = (const float*)d_in[10];
  const float* ln_g = (const float*)d_in[11]; const float* ln_b = (const float*)d_in[12];
  const float* W1 = (const float*)d_in[13]; const float* b1 = (const float*)d_in[14];
  const float* W2 = (const float*)d_in[15]; const float* b2 = (const float*)d_in[16];

  char* ws = (char*)d_ws;
  size_t off = 0;
  auto take = [&](size_t bytes) -> void* {
    void* p = ws + off;
    off += (bytes + 255) & ~(size_t)255;
    return p;
  };
  bf16_t* seqB = (bf16_t*)take((size_t)SEQL*DM*2);
  bf16_t* WeB  = (bf16_t*)take((size_t)DM*DM*2);
  bf16_t* WqB  = (bf16_t*)take((size_t)DM*DM*2);
  bf16_t* WkB  = (bf16_t*)take((size_t)DM*DM*2);
  bf16_t* WvB  = (bf16_t*)take((size_t)DM*DM*2);
  bf16_t* WoB  = (bf16_t*)take((size_t)DM*DM*2);
  bf16_t* W1B  = (bf16_t*)take((size_t)DM*FFH*2);
  bf16_t* W2B  = (bf16_t*)take((size_t)FFH*DM*2);
  float*  X    = (float*) take((size_t)SEQL*DM*4);
  bf16_t* XB   = (bf16_t*)take((size_t)SEQL*DM*2);
  bf16_t* Qf   = (bf16_t*)take((size_t)SEQL*DM*2);
  bf16_t* Kf   = (bf16_t*)take((size_t)SEQL*DM*2);
  bf16_t* Qhd  = (bf16_t*)take((size_t)SEQL*DM*2);
  bf16_t* Khd  = (bf16_t*)take((size_t)SEQL*DM*2);
  bf16_t* Vt   = (bf16_t*)take((size_t)SEQL*DM*2);
  bf16_t* Afl  = (bf16_t*)take((size_t)SEQL*DM*2);
  float*  Pp   = (float*) take((size_t)8*SEQL*DM*4);  // split-K partials (32 MB)
  float*  Xa   = (float*) take((size_t)SEQL*DM*4);
  bf16_t* XaB  = (bf16_t*)take((size_t)SEQL*DM*2);
  bf16_t* Hb   = (bf16_t*)take((size_t)SEQL*FFH*2);
  (void)ws_size; (void)in_sizes; (void)n_in; (void)out_size;

  CvtA4 cz = {};  // dummy

  // pass 0: seq (128 blocks) + emb_W (512 blocks)
  CvtA4 c0 = {};
  c0.s[0] = { seq,   seqB, 0 };
  c0.s[1] = { emb_W, WeB,  128 };
  cvt8k<2><<<dim3(640), 256, 0, stream>>>(c0);

  // embedding GEMM (split-K x4, 512 gemm blocks) + cvt Wq/Wk/Wv/Wo (2048)
  CvtA4 cq = {};
  cq.s[0] = { Wq, WqB, 0 };
  cq.s[1] = { Wk, WkB, 512 };
  cq.s[2] = { Wv, WvB, 1024 };
  cq.s[3] = { Wo, WoB, 1536 };
  gemmT<E_PART,0,64,4><<<dim3(2560), 256, 0, stream>>>(seqB, WeB, nullptr, nullptr,
      nullptr, nullptr, nullptr, Pp, nullptr, nullptr, nullptr, 16, DM, DM, 512, 512, cq);
  reduce_pos<4><<<SEQL, 256, 0, stream>>>(Pp, emb_b, X, XB);

  // fused QKV (BM=32, 768 gemm blocks) + cvt W1 (2048 blocks)
  CvtA4 c1 = {};
  c1.s[0] = { W1, W1B, 0 };
  gemmT<E_QKV,0,32,1><<<dim3(2816), 256, 0, stream>>>(XB, WqB, WkB, WvB,
      bq, bk, bv, nullptr, Qf, Kf, Vt, 48, DM, DM, DM, 768, c1);
  permute_qk<<<dim3(SEQL,2), 256, 0, stream>>>(Qf, Kf, Qhd, Khd);

  // attention (256 blocks) + cvt W2 (2048 blocks)
  CvtA4 c2 = {};
  c2.s[0] = { W2, W2B, 0 };
  attn_cvt<1><<<dim3(2304), 256, 0, stream>>>(Qhd, Khd, Vt, Afl, 256, c2);

  // output projection (split-K x4, k-permuted Wo rows) + residual + LN1
  gemmT<E_PART,1,64,0><<<dim3(512), 256, 0, stream>>>(Afl, WoB, nullptr, nullptr,
      nullptr, nullptr, nullptr, Pp, nullptr, nullptr, nullptr, 16, DM, DM, 512, 512, cz);
  reduce_ln<4,1><<<SEQL, 256, 0, stream>>>(Pp, bo, X, ln_g, ln_b, Xa, XaB);

  // FFN1 (BM=32, 1024 blocks)
  gemmT<E_FFN1,0,32,0><<<dim3(1024), 256, 0, stream>>>(XaB, W1B, nullptr, nullptr,
      b1, nullptr, nullptr, nullptr, Hb, nullptr, nullptr, 64, FFH, DM, DM, 1024, cz);

  // FFN2 (split-K x8, Kc=1024, 1024 blocks) + residual + LN2 -> out
  gemmT<E_PART,0,64,0><<<dim3(1024), 256, 0, stream>>>(Hb, W2B, nullptr, nullptr,
      nullptr, nullptr, nullptr, Pp, nullptr, nullptr, nullptr, 16, DM, FFH, 1024, 1024, cz);
  reduce_ln<8,0><<<SEQL, 256, 0, stream>>>(Pp, b2, Xa, ln_g, ln_b, (float*)d_out, nullptr);
}